// Round 12
// baseline (575.018 us; speedup 1.0000x reference)
//
#include <hip/hip_runtime.h>
#include <math.h>

constexpr int DIN = 256;
constexpr int HID = 128;
constexpr int LAT = 64;

typedef short bfrag __attribute__((ext_vector_type(8)));   // 8 bf16 (4 VGPRs)
typedef float f32x4 __attribute__((ext_vector_type(4)));

__device__ __forceinline__ float4 ld4(const float* p) { return *reinterpret_cast<const float4*>(p); }
__device__ __forceinline__ void st4(float* p, float4 v) { *reinterpret_cast<float4*>(p) = v; }

__device__ __forceinline__ unsigned short f2bf(float f) {
  unsigned int u = __float_as_uint(f);
  unsigned int r = (u + 0x7FFFu + ((u >> 16) & 1u)) >> 16;  // RNE
  return (unsigned short)r;
}

__device__ __forceinline__ float bf2f(unsigned short u) {
  return __uint_as_float(((unsigned int)u) << 16);
}

// ---------------- MFMA GEMM: xpb = x(f32) @ Wtb^T, bf16 out; attn scores fused in epilogue ----------------
__global__ __launch_bounds__(256) void gemm_xp_mfma(const float* __restrict__ xf,
                                                    const unsigned short* __restrict__ Wtb,
                                                    const float* __restrict__ att_src,
                                                    const float* __restrict__ att_dst,
                                                    unsigned short* __restrict__ xpb,
                                                    float* __restrict__ a_src, float* __restrict__ a_dst, int M) {
  __shared__ unsigned short Als[64 * 256];
  __shared__ unsigned short Bls[64 * 256];
  int t = threadIdx.x;
  int wv = t >> 6, l = t & 63, lg = l >> 4, ll = l & 15;
  int cg = blockIdx.x;
  int rt = blockIdx.y;

  {
    int row = t >> 2, seg = t & 3;
    int gr = min(rt * 64 + row, M - 1);
    const float4* src = (const float4*)(xf + (size_t)gr * 256 + seg * 64);
    int swz = (row & 7) << 4;
#pragma unroll
    for (int c = 0; c < 8; ++c) {
      float4 a = src[2 * c], b = src[2 * c + 1];
      uint4 v;
      v.x = (unsigned)f2bf(a.x) | ((unsigned)f2bf(a.y) << 16);
      v.y = (unsigned)f2bf(a.z) | ((unsigned)f2bf(a.w) << 16);
      v.z = (unsigned)f2bf(b.x) | ((unsigned)f2bf(b.y) << 16);
      v.w = (unsigned)f2bf(b.z) | ((unsigned)f2bf(b.w) << 16);
      int bo = seg * 128 + c * 16;
      *(uint4*)((char*)Als + row * 512 + (bo ^ swz)) = v;
    }
  }
  {
    int col = t >> 2, seg = t & 3;
    const uint4* src = (const uint4*)(Wtb + (size_t)(cg * 64 + col) * 256 + seg * 64);
    int swz = (col & 7) << 4;
#pragma unroll
    for (int c = 0; c < 8; ++c) {
      int bo = seg * 128 + c * 16;
      *(uint4*)((char*)Bls + col * 512 + (bo ^ swz)) = src[c];
    }
  }
  __syncthreads();

  f32x4 acc[4];
#pragma unroll
  for (int i = 0; i < 4; ++i) acc[i] = (f32x4){0.f, 0.f, 0.f, 0.f};

#pragma unroll
  for (int kt = 0; kt < 8; ++kt) {
    int ar = wv * 16 + ll;
    bfrag af = *(const bfrag*)((char*)Als + ar * 512 + ((kt * 64 + lg * 16) ^ ((ar & 7) << 4)));
#pragma unroll
    for (int fn = 0; fn < 4; ++fn) {
      int bc = fn * 16 + ll;
      bfrag bf = *(const bfrag*)((char*)Bls + bc * 512 + ((kt * 64 + lg * 16) ^ ((bc & 7) << 4)));
      acc[fn] = __builtin_amdgcn_mfma_f32_16x16x32_bf16(af, bf, acc[fn], 0, 0, 0);
    }
  }

#pragma unroll
  for (int fn = 0; fn < 4; ++fn) {
#pragma unroll
    for (int r = 0; r < 4; ++r) {
      int row = rt * 64 + wv * 16 + lg * 4 + r;
      if (row < M) xpb[(size_t)row * 512 + cg * 64 + fn * 16 + ll] = f2bf(acc[fn][r]);
    }
  }

  // ---- fused attention-score partials ----
  int h = cg >> 1;
  int c0 = (cg & 1) * 64;
  float asv[4], adv[4];
#pragma unroll
  for (int fn = 0; fn < 4; ++fn) {
    asv[fn] = att_src[h * 128 + c0 + fn * 16 + ll];
    adv[fn] = att_dst[h * 128 + c0 + fn * 16 + ll];
  }
  float ps[4] = {0.f, 0.f, 0.f, 0.f}, pd[4] = {0.f, 0.f, 0.f, 0.f};
#pragma unroll
  for (int fn = 0; fn < 4; ++fn)
#pragma unroll
    for (int r = 0; r < 4; ++r) {
      ps[r] = fmaf(acc[fn][r], asv[fn], ps[r]);
      pd[r] = fmaf(acc[fn][r], adv[fn], pd[r]);
    }
#pragma unroll
  for (int m = 8; m >= 1; m >>= 1) {
#pragma unroll
    for (int r = 0; r < 4; ++r) { ps[r] += __shfl_xor(ps[r], m); pd[r] += __shfl_xor(pd[r], m); }
  }
  if (ll == 0) {
#pragma unroll
    for (int r = 0; r < 4; ++r) {
      int row = rt * 64 + wv * 16 + lg * 4 + r;
      if (row < M) {
        atomicAdd(&a_src[row * 2 + h], ps[r]);
        atomicAdd(&a_dst[row * 2 + h], pd[r]);
      }
    }
  }
}

// ---------------- CSR build ----------------
__global__ void deg_count(const int* __restrict__ ei, int E, int Et, int* __restrict__ deg) {
  int i = blockIdx.x * blockDim.x + threadIdx.x;
  if (i >= Et) return;
  int d = (i < E) ? ei[E + i] : (i - E);
  atomicAdd(&deg[d], 1);
}

__global__ __launch_bounds__(256) void bsum_kernel(const int* __restrict__ deg, int N, int* __restrict__ bsum) {
  int t = threadIdx.x;
  int i = blockIdx.x * 256 + t;
  int v = (i < N) ? deg[i] : 0;
#pragma unroll
  for (int m = 32; m >= 1; m >>= 1) v += __shfl_xor(v, m);
  __shared__ int sh[4];
  if ((t & 63) == 0) sh[t >> 6] = v;
  __syncthreads();
  if (t == 0) bsum[blockIdx.x] = sh[0] + sh[1] + sh[2] + sh[3];
}

__global__ __launch_bounds__(256) void bscan_kernel(int* __restrict__ bsum, int B) {
  __shared__ int sh[256];
  int t = threadIdx.x;
  int v = (t < B) ? bsum[t] : 0;
  sh[t] = v;
  __syncthreads();
  for (int d = 1; d < 256; d <<= 1) {
    int x = (t >= d) ? sh[t - d] : 0;
    __syncthreads();
    sh[t] += x;
    __syncthreads();
  }
  if (t < B) bsum[t] = sh[t] - v;
}

__global__ __launch_bounds__(256) void scan_apply(const int* __restrict__ deg, const int* __restrict__ bsum, int N,
                                                  int* __restrict__ offs, int* __restrict__ cursor,
                                                  float* __restrict__ dinv) {
  int t = threadIdx.x;
  int i = blockIdx.x * 256 + t;
  int v = (i < N) ? deg[i] : 0;
  __shared__ int sh[256];
  sh[t] = v;
  __syncthreads();
  for (int d = 1; d < 256; d <<= 1) {
    int x = (t >= d) ? sh[t - d] : 0;
    __syncthreads();
    sh[t] += x;
    __syncthreads();
  }
  if (i < N) {
    int off = bsum[blockIdx.x] + sh[t] - v;
    offs[i] = off;
    cursor[i] = off;
    dinv[i] = rsqrtf((float)v);   // deg >= 1 (self-loop)
  }
}

__global__ void csr_fill(const int* __restrict__ ei, int E, int Et, int* __restrict__ cursor, int* __restrict__ csr) {
  int i = blockIdx.x * blockDim.x + threadIdx.x;
  if (i >= Et) return;
  int s, d;
  if (i < E) { s = ei[i]; d = ei[E + i]; } else { s = i - E; d = i - E; }
  int pos = atomicAdd(&cursor[d], 1);
  csr[pos] = s;
}

// ---------------- FUSED GAT: half-wave edge split, 16B row loads ----------------
// Lanes 0-31 process edges [0,dg/2), lanes 32-63 [dg/2,dg) -> 2 rows per load instr.
// Lane hl covers features 8hl..8hl+7 (uint4 = 8 bf16). Head weight: hl<16 -> head0.
// Edge-halves combined via shfl_down 32; heads via shfl_down 16.
__device__ __forceinline__ void gat_step(float2 aa, uint4 uu, float ad0, float ad1, bool headA,
                                         float& s0, float& s1, float acc[8]) {
  float e0 = aa.x + ad0; e0 = e0 >= 0.f ? e0 : 0.2f * e0;
  float e1 = aa.y + ad1; e1 = e1 >= 0.f ? e1 : 0.2f * e1;
  float x0 = __expf(e0), x1 = __expf(e1);
  s0 += x0; s1 += x1;
  float xa = headA ? x0 : x1;
  unsigned v[4] = {uu.x, uu.y, uu.z, uu.w};
#pragma unroll
  for (int q = 0; q < 4; ++q) {
    acc[2 * q]     = fmaf(bf2f((unsigned short)(v[q] & 0xFFFFu)), xa, acc[2 * q]);
    acc[2 * q + 1] = fmaf(bf2f((unsigned short)(v[q] >> 16)), xa, acc[2 * q + 1]);
  }
}

__global__ __launch_bounds__(256) void gat_fused(const int* __restrict__ offs, const int* __restrict__ deg,
                                                 const int* __restrict__ csr, const float* __restrict__ a_src,
                                                 const float* __restrict__ a_dst,
                                                 const unsigned short* __restrict__ xpb,
                                                 const float* __restrict__ bias,
                                                 float* __restrict__ h1, int N) {
  int wid = threadIdx.x >> 6, lane = threadIdx.x & 63;
  int n = blockIdx.x * 4 + wid;
  if (n >= N) return;
  int off = offs[n], dg = deg[n];
  float ad0 = a_dst[n * 2], ad1 = a_dst[n * 2 + 1];
  const float2* as2 = (const float2*)a_src;
  int hl = lane & 31;
  bool headA = hl < 16;
  int dh = dg >> 1;
  int st = (lane < 32) ? 0 : dh;
  int en = (lane < 32) ? dh : dg;

  float acc[8];
#pragma unroll
  for (int j = 0; j < 8; ++j) acc[j] = 0.f;
  float s0 = 0.f, s1 = 0.f;

  int k = st;
  for (; k + 8 <= en; k += 8) {
    int s_[8];
    float2 a_[8];
    uint4 u_[8];
#pragma unroll
    for (int q = 0; q < 8; ++q) s_[q] = csr[off + k + q];
#pragma unroll
    for (int q = 0; q < 8; ++q) a_[q] = as2[s_[q]];
#pragma unroll
    for (int q = 0; q < 8; ++q) u_[q] = *(const uint4*)(xpb + (size_t)s_[q] * 512 + 8 * hl);
#pragma unroll
    for (int q = 0; q < 8; ++q) gat_step(a_[q], u_[q], ad0, ad1, headA, s0, s1, acc);
  }
  for (; k < en; ++k) {
    int s = csr[off + k];
    float2 a = as2[s];
    uint4 u = *(const uint4*)(xpb + (size_t)s * 512 + 8 * hl);
    gat_step(a, u, ad0, ad1, headA, s0, s1, acc);
  }

  // combine edge-halves
#pragma unroll
  for (int j = 0; j < 8; ++j) acc[j] += __shfl_down(acc[j], 32);
  s0 += __shfl_down(s0, 32);
  s1 += __shfl_down(s1, 32);

  if (lane < 32) {
    float r = headA ? (1.f / s0) : (1.f / s1);
#pragma unroll
    for (int j = 0; j < 8; ++j) acc[j] *= r;
    float oth[8];
#pragma unroll
    for (int j = 0; j < 8; ++j) oth[j] = __shfl_down(acc[j], 16);   // sources lanes 16-31 (active)
    if (headA) {
      int f0 = 8 * hl;
      float4 b0 = ld4(bias + f0);
      float4 b1 = ld4(bias + f0 + 4);
      float o[8];
#pragma unroll
      for (int j = 0; j < 8; ++j) o[j] = (acc[j] + oth[j]) * 0.5f;
      float4 w0 = make_float4(fmaxf(o[0] + b0.x, 0.f), fmaxf(o[1] + b0.y, 0.f),
                              fmaxf(o[2] + b0.z, 0.f), fmaxf(o[3] + b0.w, 0.f));
      float4 w1 = make_float4(fmaxf(o[4] + b1.x, 0.f), fmaxf(o[5] + b1.y, 0.f),
                              fmaxf(o[6] + b1.z, 0.f), fmaxf(o[7] + b1.w, 0.f));
      st4(h1 + (size_t)n * 128 + f0, w0);
      st4(h1 + (size_t)n * 128 + f0 + 4, w1);
    }
  }
}

// ---------------- BatchNorm stats ----------------
template <int C>
__global__ __launch_bounds__(256) void bn_stats(const float* __restrict__ h, int N, float* __restrict__ P,
                                                float* __restrict__ PS) {
  constexpr int R = 256 / C;
  __shared__ float sh[256], sh2[256];
  int t = threadIdx.x;
  int c = t % C, r = t / C;
  float s = 0.f, ss = 0.f;
  for (int n = blockIdx.x * R + r; n < N; n += gridDim.x * R) {
    float v = h[(size_t)n * C + c];
    s += v; ss += v * v;
  }
  sh[t] = s; sh2[t] = ss;
  __syncthreads();
  if (r == 0) {
#pragma unroll
    for (int i = 1; i < R; ++i) { s += sh[i * C + c]; ss += sh2[i * C + c]; }
    P[blockIdx.x * C + c] = s;
    PS[blockIdx.x * C + c] = ss;
  }
}

// ---------------- fused BN1 reduce + fold into GCN weights, transposed bf16 out (1 block) ----------------
// Wtb2[j][k] = bf16(ssv[k] * W[k*64+j]), j<64 cols, k<128.
__global__ __launch_bounds__(256) void bn_fold_gcn(const float* __restrict__ P, const float* __restrict__ PS,
                                                   int G, int N, const float* __restrict__ g,
                                                   const float* __restrict__ b, const float* __restrict__ W,
                                                   unsigned short* __restrict__ Wtb2, float* __restrict__ cvec) {
  __shared__ float ssv[128], stv[128];
  int t = threadIdx.x;
  if (t < 128) {
    float s = 0.f, ss = 0.f;
    for (int i = 0; i < G; ++i) { s += P[i * 128 + t]; ss += PS[i * 128 + t]; }
    float mean = s / N;
    float var = ss / N - mean * mean;
    float sc = g[t] * rsqrtf(var + 1e-5f);
    ssv[t] = sc;
    stv[t] = b[t] - mean * sc;
  }
  __syncthreads();
  for (int i = t; i < 64 * 128; i += 256) {
    int j = i >> 7, k = i & 127;
    Wtb2[i] = f2bf(ssv[k] * W[k * 64 + j]);
  }
  if (t < 64) {
    float c = 0.f;
    for (int k = 0; k < 128; ++k) c += stv[k] * W[k * 64 + t];
    cvec[t] = c;
  }
}

// ---------------- fused BN2 reduce + fold into mu/lv weights (1 block) ----------------
__global__ __launch_bounds__(256) void bn_fold_mulv(const float* __restrict__ P, const float* __restrict__ PS,
                                                    int G, int N, const float* __restrict__ g,
                                                    const float* __restrict__ b,
                                                    const float* __restrict__ Wmu, const float* __restrict__ mub,
                                                    const float* __restrict__ Wlv, const float* __restrict__ lvb,
                                                    float* __restrict__ Wmuf, float* __restrict__ cmu,
                                                    float* __restrict__ Wlvf, float* __restrict__ clv) {
  __shared__ float ssv[64], stv[64];
  int t = threadIdx.x;
  if (t < 64) {
    float s = 0.f, ss = 0.f;
    for (int i = 0; i < G; ++i) { s += P[i * 64 + t]; ss += PS[i * 64 + t]; }
    float mean = s / N;
    float var = ss / N - mean * mean;
    float sc = g[t] * rsqrtf(var + 1e-5f);
    ssv[t] = sc;
    stv[t] = b[t] - mean * sc;
  }
  __syncthreads();
  for (int i = t; i < 4096; i += 256) {
    int k = i >> 6;
    Wmuf[i] = ssv[k] * Wmu[i];
    Wlvf[i] = ssv[k] * Wlv[i];
  }
  if (t < 64) {
    float cm = mub[t], cl = lvb[t];
    for (int k = 0; k < 64; ++k) { cm += stv[k] * Wmu[k * 64 + t]; cl += stv[k] * Wlv[k * 64 + t]; }
    cmu[t] = cm; clv[t] = cl;
  }
}

// ---------------- MFMA GEMM: xpb2[M,64](bf16) = h1[M,128](f32) @ Wtb2^T + cvec ----------------
__global__ __launch_bounds__(256) void gemm_h1_mfma(const float* __restrict__ h1,
                                                    const unsigned short* __restrict__ Wtb2,
                                                    const float* __restrict__ cvec,
                                                    unsigned short* __restrict__ xpb2, int M) {
  __shared__ unsigned short Als[64 * 128];  // 16 KB
  __shared__ unsigned short Bls[64 * 128];  // 16 KB
  int t = threadIdx.x;
  int wv = t >> 6, l = t & 63, lg = l >> 4, ll = l & 15;
  int m0 = blockIdx.x * 64;

  {
    int row = t >> 2, seg = t & 3;
    int gr = min(m0 + row, M - 1);
    const float4* src = (const float4*)(h1 + (size_t)gr * 128 + seg * 32);
    int swz = (row & 7) << 4;
#pragma unroll
    for (int c = 0; c < 4; ++c) {
      float4 a = src[2 * c], b = src[2 * c + 1];
      uint4 v;
      v.x = (unsigned)f2bf(a.x) | ((unsigned)f2bf(a.y) << 16);
      v.y = (unsigned)f2bf(a.z) | ((unsigned)f2bf(a.w) << 16);
      v.z = (unsigned)f2bf(b.x) | ((unsigned)f2bf(b.y) << 16);
      v.w = (unsigned)f2bf(b.z) | ((unsigned)f2bf(b.w) << 16);
      int bo = seg * 64 + c * 16;
      *(uint4*)((char*)Als + row * 256 + (bo ^ swz)) = v;
    }
  }
  {
    int col = t >> 2, seg = t & 3;
    const uint4* src = (const uint4*)(Wtb2 + col * 128 + seg * 32);
    int swz = (col & 7) << 4;
#pragma unroll
    for (int c = 0; c < 4; ++c) {
      int bo = seg * 64 + c * 16;
      *(uint4*)((char*)Bls + col * 256 + (bo ^ swz)) = src[c];
    }
  }
  __syncthreads();

  f32x4 acc[4];
#pragma unroll
  for (int i = 0; i < 4; ++i) acc[i] = (f32x4){0.f, 0.f, 0.f, 0.f};

#pragma unroll
  for (int kt = 0; kt < 4; ++kt) {
    int ar = wv * 16 + ll;
    bfrag af = *(const bfrag*)((char*)Als + ar * 256 + ((kt * 64 + lg * 16) ^ ((ar & 7) << 4)));
#pragma unroll
    for (int fn = 0; fn < 4; ++fn) {
      int bc = fn * 16 + ll;
      bfrag bf = *(const bfrag*)((char*)Bls + bc * 256 + ((kt * 64 + lg * 16) ^ ((bc & 7) << 4)));
      acc[fn] = __builtin_amdgcn_mfma_f32_16x16x32_bf16(af, bf, acc[fn], 0, 0, 0);
    }
  }

#pragma unroll
  for (int fn = 0; fn < 4; ++fn) {
    float cv = cvec[fn * 16 + ll];
#pragma unroll
    for (int r = 0; r < 4; ++r) {
      int row = m0 + wv * 16 + lg * 4 + r;
      if (row < M) xpb2[(size_t)row * 64 + fn * 16 + ll] = f2bf(acc[fn][r] + cv);
    }
  }
}

// ---------------- GCN aggregation: half-wave edge split, 4B loads ----------------
__global__ __launch_bounds__(256) void gcn_aggregate_bf(const int* __restrict__ offs, const int* __restrict__ deg,
                                                        const int* __restrict__ csr,
                                                        const unsigned short* __restrict__ xpb2,
                                                        const float* __restrict__ dinv, const float* __restrict__ bias,
                                                        float* __restrict__ g2, int N) {
  int wid = threadIdx.x >> 6, lane = threadIdx.x & 63;
  int n = blockIdx.x * 4 + wid;
  if (n >= N) return;
  int off = offs[n], dg = deg[n];
  int hl = lane & 31;
  int dh = dg >> 1;
  int st = (lane < 32) ? 0 : dh;
  int en = (lane < 32) ? dh : dg;
  float ax = 0.f, ay = 0.f;
  int k = st;
  for (; k + 8 <= en; k += 8) {
    int s_[8];
    float d_[8];
    unsigned u_[8];
#pragma unroll
    for (int q = 0; q < 8; ++q) s_[q] = csr[off + k + q];
#pragma unroll
    for (int q = 0; q < 8; ++q) d_[q] = dinv[s_[q]];
#pragma unroll
    for (int q = 0; q < 8; ++q) u_[q] = *(const unsigned*)(xpb2 + (size_t)s_[q] * 64 + 2 * hl);
#pragma unroll
    for (int q = 0; q < 8; ++q) {
      ax = fmaf(bf2f((unsigned short)(u_[q] & 0xFFFFu)), d_[q], ax);
      ay = fmaf(bf2f((unsigned short)(u_[q] >> 16)), d_[q], ay);
    }
  }
  for (; k < en; ++k) {
    int s = csr[off + k];
    float d = dinv[s];
    unsigned u = *(const unsigned*)(xpb2 + (size_t)s * 64 + 2 * hl);
    ax = fmaf(bf2f((unsigned short)(u & 0xFFFFu)), d, ax);
    ay = fmaf(bf2f((unsigned short)(u >> 16)), d, ay);
  }
  ax += __shfl_down(ax, 32);
  ay += __shfl_down(ay, 32);
  if (lane < 32) {
    float dn = dinv[n];
    float2 b = *(const float2*)(bias + 2 * hl);
    float2 o;
    o.x = fmaxf(ax * dn + b.x, 0.f);
    o.y = fmaxf(ay * dn + b.y, 0.f);
    *(float2*)(g2 + (size_t)n * 64 + 2 * hl) = o;
  }
}

// ---------------- fused tail: mu/lv GEMMs + reparam + res GEMM (64x64 tile, K=64) ----------------
__global__ __launch_bounds__(256) void tail_fused(const float* __restrict__ g2,
                                                  const float* __restrict__ Wmuf, const float* __restrict__ cmu,
                                                  const float* __restrict__ Wlvf, const float* __restrict__ clv,
                                                  const float* __restrict__ resW, const float* __restrict__ resb,
                                                  const float* __restrict__ eps,
                                                  float* __restrict__ mu, float* __restrict__ lv,
                                                  unsigned short* __restrict__ rzb, int N) {
  __shared__ float Gs[64][68];
  __shared__ float Wm[64][64];
  __shared__ float Wl[64][64];
  __shared__ float Rw[64][64];
  int t = threadIdx.x;
  int m0 = blockIdx.x * 64;
  int tm = t & 15, tn = t >> 4;

#pragma unroll
  for (int i = 0; i < 4; ++i) {
    int f4 = t + i * 256;
    int row = f4 >> 4;
    int k4 = (f4 & 15) << 2;
    int gr = m0 + row;
    float4 v = make_float4(0.f, 0.f, 0.f, 0.f);
    if (gr < N) v = ld4(g2 + (size_t)gr * 64 + k4);
    Gs[k4 + 0][row] = v.x; Gs[k4 + 1][row] = v.y; Gs[k4 + 2][row] = v.z; Gs[k4 + 3][row] = v.w;
    st4(&Wm[f4 >> 4][k4], ld4(Wmuf + f4 * 4));
    st4(&Wl[f4 >> 4][k4], ld4(Wlvf + f4 * 4));
    st4(&Rw[f4 >> 4][k4], ld4(resW + f4 * 4));
  }
  __syncthreads();

  float am[4][4], al[4][4];
#pragma unroll
  for (int i = 0; i < 4; ++i)
#pragma unroll
    for (int j = 0; j < 4; ++j) { am[i][j] = 0.f; al[i][j] = 0.f; }

#pragma unroll 8
  for (int k = 0; k < 64; ++k) {
    float4 a = ld4(&Gs[k][tm << 2]);
    float4 bm = ld4(&Wm[k][tn << 2]);
    float4 bl = ld4(&Wl[k][tn << 2]);
    float av[4] = {a.x, a.y, a.z, a.w};
    float bmv[4] = {bm.x, bm.y, bm.z, bm.w};
    float blv[4] = {bl.x, bl.y, bl.z, bl.w};
#pragma unroll
    for (int i = 0; i < 4; ++i)
#pragma unroll
      for (int j = 0; j < 4; ++j) {
        am[i][j] = fmaf(av[i], bmv[j], am[i][j]);
        al[i][j] = fmaf(av[i], blv[j], al[i][j]);
      }
  }

  int nb = tn << 2;
  float cm4[4] = {cmu[nb], cmu[nb + 1], cmu[nb + 2], cmu[nb + 3]};
  float cl4[4] = {clv[nb], clv[nb + 1], clv[nb + 2], clv[nb + 3]};
  float zreg[4][4];
#pragma unroll
  for (int i = 0; i < 4; ++i) {
    int gr = m0 + (tm << 2) + i;
    if (gr < N) {
      float4 ep = ld4(eps + (size_t)gr * 64 + nb);
      float epv[4] = {ep.x, ep.y, ep.z, ep.w};
      float muv[4], lvv[4];
#pragma unroll
      for (int j = 0; j < 4; ++j) {
        muv[j] = am[i][j] + cm4[j];
        lvv[j] = al[i][j] + cl4[j];
        zreg[i][j] = fmaf(epv[j], __expf(0.5f * lvv[j]), muv[j]);
      }
      st4(mu + (size_t)gr * 64 + nb, make_float4(muv[0], muv[1], muv[2], muv[3]));
      st4(lv + (size_t)gr * 64 + nb, make_float4(lvv[0], lvv[1], lvv[2], lvv[3]));
    } else {
#pragma unroll
      for (int j = 0; j < 4; ++j) zreg[i][j] = 0.f;
    }
  }

  __syncthreads();
#pragma unroll
  for (int i = 0; i < 4; ++i)
#pragma unroll
    for (int j = 0; j < 4; ++j) Gs[(tn << 2) + j][(tm << 2) + i] = zreg[i][j];
  __syncthreads();

  float ar[4][4];
#pragma unroll
  for (int i = 0; i < 4; ++i)
#pragma unroll
    for (int j = 0; j < 4; ++j) ar[i][j] = 0.f;
#pragma unroll 8
  for (int k = 0; k < 64; ++k) {
    float4 a = ld4(&Gs[k][tm << 2]);
    float4 b = ld4(&Rw[k][tn << 2]);
    float av[4] = {a.x, a.y, a.z, a.w};
    float bv[4] = {b.x, b.y, b.z, b.w};
#pragma unroll
    for (int i = 0; i < 4; ++i)
#pragma unroll
      for (int j = 0; j < 4; ++j) ar[i][j] = fmaf(av[i], bv[j], ar[i][j]);
  }
  float rb4[4] = {resb[nb], resb[nb + 1], resb[nb + 2], resb[nb + 3]};
#pragma unroll
  for (int i = 0; i < 4; ++i) {
    int gr = m0 + (tm << 2) + i;
    if (gr < N) {
      ushort4 o;
      o.x = f2bf(ar[i][0] + rb4[0]);
      o.y = f2bf(ar[i][1] + rb4[1]);
      o.z = f2bf(ar[i][2] + rb4[2]);
      o.w = f2bf(ar[i][3] + rb4[3]);
      *(ushort4*)(rzb + (size_t)gr * 64 + nb) = o;
    }
  }
}

// ---------------- prep gat_W -> transposed bf16 Wtb[col][k] ----------------
__global__ void prep_gatW(const float* __restrict__ W, unsigned short* __restrict__ Wtb) {
  int i = blockIdx.x * blockDim.x + threadIdx.x;
  if (i >= 256 * 256) return;
  int col = i >> 8, k = i & 255;
  Wtb[i] = f2bf(W[k * 256 + col]);
}

// ---------------- prep W1 → bf16 decoder layout [4 kt][256 j][40 kp] (padded) ----------------
__global__ void prep_W1(const float* __restrict__ W1, unsigned short* __restrict__ W1t) {
  int i = blockIdx.x * blockDim.x + threadIdx.x;
  if (i >= 4 * 256 * 40) return;
  int kt = i / 10240;
  int rem = i - kt * 10240;
  int j = rem / 40;
  int kp = rem - j * 40;
  float v = (kp < 32) ? W1[(size_t)(kt * 32 + kp) * 256 + j] : 0.f;
  W1t[i] = f2bf(v);
}

// ---------------- MFMA decoder (64 edges, 4 waves, B per-kt in LDS) ----------------
__global__ __launch_bounds__(256) void decoder_mfma(const int* __restrict__ ei, int E,
                                                    const unsigned short* __restrict__ rzb,
                                                    const unsigned short* __restrict__ W1t,
                                                    const float* __restrict__ b1, const float* __restrict__ W2,
                                                    const float* __restrict__ b2, float* __restrict__ recon) {
  __shared__ unsigned short Als[64 * 128];   // 16 KB
  __shared__ unsigned short Bls[256 * 40];   // 20 KB
  __shared__ float red[4][64];
  int t = threadIdx.x;
  int wv = t >> 6, l = t & 63;
  int lg = l >> 4, ll = l & 15;
  int e0 = blockIdx.x * 64;

  {
    int e = t >> 2;
    int part = (t >> 1) & 1;
    int half = t & 1;
    int eg = e0 + e;
    if (eg >= E) eg = E - 1;
    int r = (part == 0) ? ei[eg] : ei[E + eg];
    const uint4* gsrc = (const uint4*)(rzb + (size_t)r * 64 + half * 32);
    int bo0 = part * 128 + half * 64;
    int swz = (e & 7) << 4;
#pragma unroll
    for (int c = 0; c < 4; ++c) {
      uint4 v = gsrc[c];
      int bo = bo0 + c * 16;
      *(uint4*)&Als[e * 128 + ((bo ^ swz) >> 1)] = v;
    }
  }

  f32x4 acc[4][4];
#pragma unroll
  for (int a = 0; a < 4; ++a)
#pragma unroll
    for (int b = 0; b < 4; ++b) acc[a][b] = (f32x4){0.f, 0.f, 0.f, 0.f};

  for (int kt = 0; kt < 4; ++kt) {
    __syncthreads();
    {
      const uint4* gsrc = (const uint4*)(W1t + kt * 10240);
      uint4* ldst = (uint4*)Bls;
#pragma unroll
      for (int i = 0; i < 5; ++i) ldst[t + i * 256] = gsrc[t + i * 256];
    }
    __syncthreads();

    bfrag af[4];
#pragma unroll
    for (int fm = 0; fm < 4; ++fm) {
      int e = fm * 16 + ll;
      int bo = kt * 64 + lg * 16;
      af[fm] = *(const bfrag*)&Als[e * 128 + ((bo ^ ((e & 7) << 4)) >> 1)];
    }
#pragma unroll
    for (int fn = 0; fn < 4; ++fn) {
      int j = wv * 64 + fn * 16 + ll;
      bfrag bf = *(const bfrag*)&Bls[j * 40 + lg * 8];
#pragma unroll
      for (int fm = 0; fm < 4; ++fm)
        acc[fm][fn] = __builtin_amdgcn_mfma_f32_16x16x32_bf16(af[fm], bf, acc[fm][fn], 0, 0, 0);
    }
  }

  float bj[4], wj[4];
#pragma unroll
  for (int fn = 0; fn < 4; ++fn) {
    int j = wv * 64 + fn * 16 + ll;
    bj[fn] = b1[j];
    wj[fn] = W2[j];
  }
#pragma unroll
  for (int fm = 0; fm < 4; ++fm) {
    float pr[4] = {0.f, 0.f, 0.f, 0.f};
#pragma unroll
    for (int fn = 0; fn < 4; ++fn) {
#pragma unroll
      for (int r = 0; r < 4; ++r)
        pr[r] = fmaf(fmaxf(acc[fm][fn][r] + bj[fn], 0.f), wj[fn], pr[r]);
    }
#pragma unroll
    for (int m = 8; m >= 1; m >>= 1) {
#pragma unroll
      for (int r = 0; r < 4; ++r) pr[r] += __shfl_xor(pr[r], m);
    }
    if (ll == 0) {
#pragma unroll
      for (int r = 0; r < 4; ++r) red[wv][fm * 16 + lg * 4 + r] = pr[r];
    }
  }
  __syncthreads();
  if (t < 64) {
    int eg = e0 + t;
    if (eg < E) recon[eg] = red[0][t] + red[1][t] + red[2][t] + red[3][t] + b2[0];
  }
}

extern "C" void kernel_launch(void* const* d_in, const int* in_sizes, int n_in,
                              void* d_out, int out_size, void* d_ws, size_t ws_size,
                              hipStream_t stream) {
  const float* x = (const float*)d_in[0];
  const int* ei = (const int*)d_in[1];
  const float* gat_W = (const float*)d_in[2];
  const float* att_src = (const float*)d_in[3];
  const float* att_dst = (const float*)d_in[4];
  const float* gat_bias = (const float*)d_in[5];
  const float* bn1_g = (const float*)d_in[6];
  const float* bn1_b = (const float*)d_in[7];
  const float* gcn_W = (const float*)d_in[8];
  const float* gcn_bias = (const float*)d_in[9];
  const float* bn2_g = (const float*)d_in[10];
  const float* bn2_b = (const float*)d_in[11];
  const float* mu_W = (const float*)d_in[12];
  const float* mu_b = (const float*)d_in[13];
  const float* lv_W = (const float*)d_in[14];
  const float* lv_b = (const float*)d_in[15];
  const float* res_W = (const float*)d_in[16];
  const float* res_b = (const float*)d_in[17];
  const float* dec_W1 = (const float*)d_in[18];
  const float* dec_b1 = (const float*)d_in[19];
  const float* dec_W2 = (const float*)d_in[20];
  const float* dec_b2 = (const float*)d_in[21];
  const float* eps = (const float*)d_in[22];

  int N = in_sizes[0] / DIN;   // 50000
  int E = in_sizes[1] / 2;     // 800000
  int Et = E + N;
  int NB = (N + 255) / 256;    // scan chunks (<= 256)

  float* ws = (float*)d_ws;
  size_t off = 0;
  float* xp = ws; off += (size_t)N * 256;
  unsigned short* xpb = (unsigned short*)xp;    // bf16 xp rows, stride 512 ushorts
  unsigned short* xpb2 = (unsigned short*)xp;   // bf16 xp2 [N,64] (xpb dead by then)
  float* g2 = xp + (size_t)N * 64;
  float* rz = xp + (size_t)N * 192;
  unsigned short* rzb = (unsigned short*)rz;    // bf16 res_z [N,64]
  float* h1 = ws + off; off += (size_t)N * 128;
  float* a_src = ws + off; off += (size_t)2 * N;
  float* a_dst = ws + off; off += (size_t)2 * N;
  float* dinv = ws + off; off += N;
  float* P = ws + off; off += 128 * 128;
  float* PS = ws + off; off += 128 * 128;
  unsigned short* Wtb2 = (unsigned short*)(ws + off); off += 128 * 64;   // 64x128 bf16 (in old W2f slot)
  float* c2 = ws + off; off += 64;
  float* Wmuf = ws + off; off += 64 * 64;
  float* cmu = ws + off; off += 64;
  float* Wlvf = ws + off; off += 64 * 64;
  float* clv = ws + off; off += 64;
  unsigned short* W1t = (unsigned short*)(ws + off); off += 20480;   // 4*256*40 bf16
  unsigned short* Wtb = (unsigned short*)(ws + off); off += 32768;   // 256*256 bf16
  int* deg = (int*)(ws + off); off += N;
  int* offs = (int*)(ws + off); off += N;
  int* cursor = (int*)(ws + off); off += N;
  int* bsum = (int*)(ws + off); off += 256;
  int* csr = (int*)(ws + off); off += Et;

  float* recon = (float*)d_out;
  float* mu = recon + E;
  float* lv = mu + (size_t)N * LAT;

  // 0. weight preps + zero attn-score accumulators (a_src/a_dst contiguous)
  prep_W1<<<(4 * 256 * 40 + 255) / 256, 256, 0, stream>>>(dec_W1, W1t);
  prep_gatW<<<(256 * 256 + 255) / 256, 256, 0, stream>>>(gat_W, Wtb);
  hipMemsetAsync(a_src, 0, (size_t)4 * N * sizeof(float), stream);

  // 1. xp = x @ gat_W via MFMA; attention scores fused (atomic partials)
  dim3 gX(4, (N + 63) / 64);
  gemm_xp_mfma<<<gX, 256, 0, stream>>>(x, Wtb, att_src, att_dst, xpb, a_src, a_dst, N);

  // 2. CSR build (parallel 3-phase scan)
  hipMemsetAsync(deg, 0, (size_t)N * sizeof(int), stream);
  deg_count<<<(Et + 255) / 256, 256, 0, stream>>>(ei, E, Et, deg);
  bsum_kernel<<<NB, 256, 0, stream>>>(deg, N, bsum);
  bscan_kernel<<<1, 256, 0, stream>>>(bsum, NB);
  scan_apply<<<NB, 256, 0, stream>>>(deg, bsum, N, offs, cursor, dinv);
  csr_fill<<<(Et + 255) / 256, 256, 0, stream>>>(ei, E, Et, cursor, csr);

  // 3. fused GAT softmax + aggregation (half-wave edge split, 16B loads)
  gat_fused<<<(N + 3) / 4, 256, 0, stream>>>(offs, deg, csr, a_src, a_dst, xpb, gat_bias, h1, N);

  // 4. BN1 reduce+fold (transposed bf16 weights); xp2 (bf16) = h1 @ W2f + c2 via MFMA
  bn_stats<128><<<128, 256, 0, stream>>>(h1, N, P, PS);
  bn_fold_gcn<<<1, 256, 0, stream>>>(P, PS, 128, N, bn1_g, bn1_b, gcn_W, Wtb2, c2);
  gemm_h1_mfma<<<(N + 63) / 64, 256, 0, stream>>>(h1, Wtb2, c2, xpb2, N);

  // 5. GCN aggregation (half-wave edge split, 4B loads)
  gcn_aggregate_bf<<<(N + 3) / 4, 256, 0, stream>>>(offs, deg, csr, xpb2, dinv, gcn_bias, g2, N);

  // 6. BN2 reduce+fold; fused tail (mu, lv, reparam, res GEMM in one kernel)
  bn_stats<64><<<128, 256, 0, stream>>>(g2, N, P, PS);
  bn_fold_mulv<<<1, 256, 0, stream>>>(P, PS, 128, N, bn2_g, bn2_b, mu_W, mu_b, lv_W, lv_b,
                                      Wmuf, cmu, Wlvf, clv);
  tail_fused<<<(N + 63) / 64, 256, 0, stream>>>(g2, Wmuf, cmu, Wlvf, clv, res_W, res_b, eps,
                                                mu, lv, rzb, N);

  // 7. MFMA decoder
  decoder_mfma<<<(E + 63) / 64, 256, 0, stream>>>(ei, E, rzb, W1t, dec_b1, dec_W2, dec_b2, recon);
}

// Round 13
// 569.882 us; speedup vs baseline: 1.0090x; 1.0090x over previous
//
#include <hip/hip_runtime.h>
#include <math.h>

constexpr int DIN = 256;
constexpr int HID = 128;
constexpr int LAT = 64;

typedef short bfrag __attribute__((ext_vector_type(8)));   // 8 bf16 (4 VGPRs)
typedef float f32x4 __attribute__((ext_vector_type(4)));

__device__ __forceinline__ float4 ld4(const float* p) { return *reinterpret_cast<const float4*>(p); }
__device__ __forceinline__ void st4(float* p, float4 v) { *reinterpret_cast<float4*>(p) = v; }

__device__ __forceinline__ unsigned short f2bf(float f) {
  unsigned int u = __float_as_uint(f);
  unsigned int r = (u + 0x7FFFu + ((u >> 16) & 1u)) >> 16;  // RNE
  return (unsigned short)r;
}

__device__ __forceinline__ float bf2f(unsigned short u) {
  return __uint_as_float(((unsigned int)u) << 16);
}

// ---------------- f32 GEMM with bf16 output: Cb[M,N](bf16) = A[M,K] @ B[K,N] + crow ----------------
__global__ __launch_bounds__(256) void gemm64b(const float* __restrict__ A, const float* __restrict__ B,
                                               const float* __restrict__ crow, unsigned short* __restrict__ Cb,
                                               int M, int N, int K) {
  __shared__ float As[32][68];
  __shared__ float Bs[32][68];
  int t = threadIdx.x;
  int m0 = blockIdx.x * 64, n0 = blockIdx.y * 64;
  int tm = t & 15, tn = t >> 4;
  float acc[4][4];
#pragma unroll
  for (int i = 0; i < 4; i++)
#pragma unroll
    for (int j = 0; j < 4; j++) acc[i][j] = 0.f;

  for (int kt = 0; kt < K; kt += 32) {
#pragma unroll
    for (int i = 0; i < 2; ++i) {
      int f4 = t + i * 256;
      int m = f4 >> 3;
      int k4 = (f4 & 7) << 2;
      int gm = m0 + m;
      float4 v = make_float4(0.f, 0.f, 0.f, 0.f);
      if (gm < M) v = ld4(A + (size_t)gm * K + kt + k4);
      As[k4 + 0][m] = v.x; As[k4 + 1][m] = v.y; As[k4 + 2][m] = v.z; As[k4 + 3][m] = v.w;
    }
#pragma unroll
    for (int i = 0; i < 2; ++i) {
      int f4 = t + i * 256;
      int k = f4 >> 4;
      int n4 = (f4 & 15) << 2;
      float4 v = ld4(B + (size_t)(kt + k) * N + n0 + n4);
      st4(&Bs[k][n4], v);
    }
    __syncthreads();
#pragma unroll
    for (int k = 0; k < 32; ++k) {
      float4 a = ld4(&As[k][tm << 2]);
      float4 b = ld4(&Bs[k][tn << 2]);
      float av[4] = {a.x, a.y, a.z, a.w};
      float bv[4] = {b.x, b.y, b.z, b.w};
#pragma unroll
      for (int i = 0; i < 4; i++)
#pragma unroll
        for (int j = 0; j < 4; j++) acc[i][j] = fmaf(av[i], bv[j], acc[i][j]);
    }
    __syncthreads();
  }
#pragma unroll
  for (int i = 0; i < 4; ++i) {
    int gm = m0 + (tm << 2) + i;
    if (gm < M) {
      int nb = n0 + (tn << 2);
      ushort4 o;
      o.x = f2bf(acc[i][0] + crow[nb]);
      o.y = f2bf(acc[i][1] + crow[nb + 1]);
      o.z = f2bf(acc[i][2] + crow[nb + 2]);
      o.w = f2bf(acc[i][3] + crow[nb + 3]);
      *(ushort4*)(Cb + (size_t)gm * N + nb) = o;
    }
  }
}

// ---------------- MFMA GEMM: xpb = x(f32) @ Wtb^T, bf16 out; attn scores fused in epilogue ----------------
__global__ __launch_bounds__(256) void gemm_xp_mfma(const float* __restrict__ xf,
                                                    const unsigned short* __restrict__ Wtb,
                                                    const float* __restrict__ att_src,
                                                    const float* __restrict__ att_dst,
                                                    unsigned short* __restrict__ xpb,
                                                    float* __restrict__ a_src, float* __restrict__ a_dst, int M) {
  __shared__ unsigned short Als[64 * 256];
  __shared__ unsigned short Bls[64 * 256];
  int t = threadIdx.x;
  int wv = t >> 6, l = t & 63, lg = l >> 4, ll = l & 15;
  int cg = blockIdx.x;
  int rt = blockIdx.y;

  {
    int row = t >> 2, seg = t & 3;
    int gr = min(rt * 64 + row, M - 1);
    const float4* src = (const float4*)(xf + (size_t)gr * 256 + seg * 64);
    int swz = (row & 7) << 4;
#pragma unroll
    for (int c = 0; c < 8; ++c) {
      float4 a = src[2 * c], b = src[2 * c + 1];
      uint4 v;
      v.x = (unsigned)f2bf(a.x) | ((unsigned)f2bf(a.y) << 16);
      v.y = (unsigned)f2bf(a.z) | ((unsigned)f2bf(a.w) << 16);
      v.z = (unsigned)f2bf(b.x) | ((unsigned)f2bf(b.y) << 16);
      v.w = (unsigned)f2bf(b.z) | ((unsigned)f2bf(b.w) << 16);
      int bo = seg * 128 + c * 16;
      *(uint4*)((char*)Als + row * 512 + (bo ^ swz)) = v;
    }
  }
  {
    int col = t >> 2, seg = t & 3;
    const uint4* src = (const uint4*)(Wtb + (size_t)(cg * 64 + col) * 256 + seg * 64);
    int swz = (col & 7) << 4;
#pragma unroll
    for (int c = 0; c < 8; ++c) {
      int bo = seg * 128 + c * 16;
      *(uint4*)((char*)Bls + col * 512 + (bo ^ swz)) = src[c];
    }
  }
  __syncthreads();

  f32x4 acc[4];
#pragma unroll
  for (int i = 0; i < 4; ++i) acc[i] = (f32x4){0.f, 0.f, 0.f, 0.f};

#pragma unroll
  for (int kt = 0; kt < 8; ++kt) {
    int ar = wv * 16 + ll;
    bfrag af = *(const bfrag*)((char*)Als + ar * 512 + ((kt * 64 + lg * 16) ^ ((ar & 7) << 4)));
#pragma unroll
    for (int fn = 0; fn < 4; ++fn) {
      int bc = fn * 16 + ll;
      bfrag bf = *(const bfrag*)((char*)Bls + bc * 512 + ((kt * 64 + lg * 16) ^ ((bc & 7) << 4)));
      acc[fn] = __builtin_amdgcn_mfma_f32_16x16x32_bf16(af, bf, acc[fn], 0, 0, 0);
    }
  }

#pragma unroll
  for (int fn = 0; fn < 4; ++fn) {
#pragma unroll
    for (int r = 0; r < 4; ++r) {
      int row = rt * 64 + wv * 16 + lg * 4 + r;
      if (row < M) xpb[(size_t)row * 512 + cg * 64 + fn * 16 + ll] = f2bf(acc[fn][r]);
    }
  }

  // ---- fused attention-score partials ----
  int h = cg >> 1;
  int c0 = (cg & 1) * 64;
  float asv[4], adv[4];
#pragma unroll
  for (int fn = 0; fn < 4; ++fn) {
    asv[fn] = att_src[h * 128 + c0 + fn * 16 + ll];
    adv[fn] = att_dst[h * 128 + c0 + fn * 16 + ll];
  }
  float ps[4] = {0.f, 0.f, 0.f, 0.f}, pd[4] = {0.f, 0.f, 0.f, 0.f};
#pragma unroll
  for (int fn = 0; fn < 4; ++fn)
#pragma unroll
    for (int r = 0; r < 4; ++r) {
      ps[r] = fmaf(acc[fn][r], asv[fn], ps[r]);
      pd[r] = fmaf(acc[fn][r], adv[fn], pd[r]);
    }
#pragma unroll
  for (int m = 8; m >= 1; m >>= 1) {
#pragma unroll
    for (int r = 0; r < 4; ++r) { ps[r] += __shfl_xor(ps[r], m); pd[r] += __shfl_xor(pd[r], m); }
  }
  if (ll == 0) {
#pragma unroll
    for (int r = 0; r < 4; ++r) {
      int row = rt * 64 + wv * 16 + lg * 4 + r;
      if (row < M) {
        atomicAdd(&a_src[row * 2 + h], ps[r]);
        atomicAdd(&a_dst[row * 2 + h], pd[r]);
      }
    }
  }
}

// ---------------- CSR build ----------------
__global__ void deg_count(const int* __restrict__ ei, int E, int Et, int* __restrict__ deg) {
  int i = blockIdx.x * blockDim.x + threadIdx.x;
  if (i >= Et) return;
  int d = (i < E) ? ei[E + i] : (i - E);
  atomicAdd(&deg[d], 1);
}

__global__ __launch_bounds__(256) void bsum_kernel(const int* __restrict__ deg, int N, int* __restrict__ bsum) {
  int t = threadIdx.x;
  int i = blockIdx.x * 256 + t;
  int v = (i < N) ? deg[i] : 0;
#pragma unroll
  for (int m = 32; m >= 1; m >>= 1) v += __shfl_xor(v, m);
  __shared__ int sh[4];
  if ((t & 63) == 0) sh[t >> 6] = v;
  __syncthreads();
  if (t == 0) bsum[blockIdx.x] = sh[0] + sh[1] + sh[2] + sh[3];
}

__global__ __launch_bounds__(256) void bscan_kernel(int* __restrict__ bsum, int B) {
  __shared__ int sh[256];
  int t = threadIdx.x;
  int v = (t < B) ? bsum[t] : 0;
  sh[t] = v;
  __syncthreads();
  for (int d = 1; d < 256; d <<= 1) {
    int x = (t >= d) ? sh[t - d] : 0;
    __syncthreads();
    sh[t] += x;
    __syncthreads();
  }
  if (t < B) bsum[t] = sh[t] - v;
}

__global__ __launch_bounds__(256) void scan_apply(const int* __restrict__ deg, const int* __restrict__ bsum, int N,
                                                  int* __restrict__ offs, int* __restrict__ cursor,
                                                  float* __restrict__ dinv) {
  int t = threadIdx.x;
  int i = blockIdx.x * 256 + t;
  int v = (i < N) ? deg[i] : 0;
  __shared__ int sh[256];
  sh[t] = v;
  __syncthreads();
  for (int d = 1; d < 256; d <<= 1) {
    int x = (t >= d) ? sh[t - d] : 0;
    __syncthreads();
    sh[t] += x;
    __syncthreads();
  }
  if (i < N) {
    int off = bsum[blockIdx.x] + sh[t] - v;
    offs[i] = off;
    cursor[i] = off;
    dinv[i] = rsqrtf((float)v);   // deg >= 1 (self-loop)
  }
}

__global__ void csr_fill(const int* __restrict__ ei, int E, int Et, int* __restrict__ cursor, int* __restrict__ csr) {
  int i = blockIdx.x * blockDim.x + threadIdx.x;
  if (i >= Et) return;
  int s, d;
  if (i < E) { s = ei[i]; d = ei[E + i]; } else { s = i - E; d = i - E; }
  int pos = atomicAdd(&cursor[d], 1);
  csr[pos] = s;
}

// ---------------- FUSED GAT, no-max softmax, 8-way unrolled gather (wave per node) ----------------
__global__ __launch_bounds__(256) void gat_fused(const int* __restrict__ offs, const int* __restrict__ deg,
                                                 const int* __restrict__ csr, const float* __restrict__ a_src,
                                                 const float* __restrict__ a_dst,
                                                 const unsigned short* __restrict__ xpb,
                                                 const float* __restrict__ bias,
                                                 float* __restrict__ h1, int N) {
  int wid = threadIdx.x >> 6, lane = threadIdx.x & 63;
  int n = blockIdx.x * 4 + wid;
  if (n >= N) return;
  int off = offs[n], dg = deg[n];
  float ad0 = a_dst[n * 2], ad1 = a_dst[n * 2 + 1];
  const float2* as2 = (const float2*)a_src;

  float4 acc = make_float4(0.f, 0.f, 0.f, 0.f);
  float s0 = 0.f, s1 = 0.f;
  bool h0 = lane < 32;

#define GAT_STEP(aa, uu)                                         \
  {                                                              \
    float e0 = (aa).x + ad0; e0 = e0 >= 0.f ? e0 : 0.2f * e0;    \
    float e1 = (aa).y + ad1; e1 = e1 >= 0.f ? e1 : 0.2f * e1;    \
    float x0 = __expf(e0), x1 = __expf(e1);                      \
    s0 += x0; s1 += x1;                                          \
    float xa = h0 ? x0 : x1;                                     \
    acc.x = fmaf(bf2f((uu).x), xa, acc.x);                       \
    acc.y = fmaf(bf2f((uu).y), xa, acc.y);                       \
    acc.z = fmaf(bf2f((uu).z), xa, acc.z);                       \
    acc.w = fmaf(bf2f((uu).w), xa, acc.w);                       \
  }

  int k = 0;
  for (; k + 8 <= dg; k += 8) {
    int s_[8];
#pragma unroll
    for (int q = 0; q < 8; ++q) s_[q] = csr[off + k + q];
    float2 a_[8];
    ushort4 u_[8];
#pragma unroll
    for (int q = 0; q < 8; ++q) a_[q] = as2[s_[q]];
#pragma unroll
    for (int q = 0; q < 8; ++q) u_[q] = ((const ushort4*)(xpb + (size_t)s_[q] * 512))[lane];
#pragma unroll
    for (int q = 0; q < 8; ++q) GAT_STEP(a_[q], u_[q]);
  }
  for (; k + 4 <= dg; k += 4) {
    int sa = csr[off + k], sb = csr[off + k + 1], sc = csr[off + k + 2], sd = csr[off + k + 3];
    float2 aa = as2[sa], ab = as2[sb], ac = as2[sc], ad = as2[sd];
    ushort4 ua = ((const ushort4*)(xpb + (size_t)sa * 512))[lane];
    ushort4 ub = ((const ushort4*)(xpb + (size_t)sb * 512))[lane];
    ushort4 uc = ((const ushort4*)(xpb + (size_t)sc * 512))[lane];
    ushort4 ud = ((const ushort4*)(xpb + (size_t)sd * 512))[lane];
    GAT_STEP(aa, ua); GAT_STEP(ab, ub); GAT_STEP(ac, uc); GAT_STEP(ad, ud);
  }
  for (; k < dg; ++k) {
    int s = csr[off + k];
    float2 a = as2[s];
    ushort4 u = ((const ushort4*)(xpb + (size_t)s * 512))[lane];
    GAT_STEP(a, u);
  }
#undef GAT_STEP

  float r = h0 ? (1.f / s0) : (1.f / s1);
  acc.x *= r; acc.y *= r; acc.z *= r; acc.w *= r;

  float ox = __shfl_down(acc.x, 32);
  float oy = __shfl_down(acc.y, 32);
  float oz = __shfl_down(acc.z, 32);
  float ow = __shfl_down(acc.w, 32);
  if (h0) {
    int f4 = lane << 2;
    float4 b = ld4(bias + f4);
    float4 o;
    o.x = fmaxf(0.f, (acc.x + ox) * 0.5f + b.x);
    o.y = fmaxf(0.f, (acc.y + oy) * 0.5f + b.y);
    o.z = fmaxf(0.f, (acc.z + oz) * 0.5f + b.z);
    o.w = fmaxf(0.f, (acc.w + ow) * 0.5f + b.w);
    st4(h1 + (size_t)n * 128 + f4, o);
  }
}

// ---------------- BatchNorm stats ----------------
template <int C>
__global__ __launch_bounds__(256) void bn_stats(const float* __restrict__ h, int N, float* __restrict__ P,
                                                float* __restrict__ PS) {
  constexpr int R = 256 / C;
  __shared__ float sh[256], sh2[256];
  int t = threadIdx.x;
  int c = t % C, r = t / C;
  float s = 0.f, ss = 0.f;
  for (int n = blockIdx.x * R + r; n < N; n += gridDim.x * R) {
    float v = h[(size_t)n * C + c];
    s += v; ss += v * v;
  }
  sh[t] = s; sh2[t] = ss;
  __syncthreads();
  if (r == 0) {
#pragma unroll
    for (int i = 1; i < R; ++i) { s += sh[i * C + c]; ss += sh2[i * C + c]; }
    P[blockIdx.x * C + c] = s;
    PS[blockIdx.x * C + c] = ss;
  }
}

// ---------------- fused BN1 reduce + fold into GCN weights (1 block) ----------------
__global__ __launch_bounds__(256) void bn_fold_gcn(const float* __restrict__ P, const float* __restrict__ PS,
                                                   int G, int N, const float* __restrict__ g,
                                                   const float* __restrict__ b, const float* __restrict__ W,
                                                   float* __restrict__ Wf, float* __restrict__ cvec) {
  __shared__ float ssv[128], stv[128];
  int t = threadIdx.x;
  if (t < 128) {
    float s = 0.f, ss = 0.f;
    for (int i = 0; i < G; ++i) { s += P[i * 128 + t]; ss += PS[i * 128 + t]; }
    float mean = s / N;
    float var = ss / N - mean * mean;
    float sc = g[t] * rsqrtf(var + 1e-5f);
    ssv[t] = sc;
    stv[t] = b[t] - mean * sc;
  }
  __syncthreads();
  for (int i = t; i < 128 * 64; i += 256) {
    int k = i >> 6;
    Wf[i] = ssv[k] * W[i];
  }
  if (t < 64) {
    float c = 0.f;
    for (int k = 0; k < 128; ++k) c += stv[k] * W[k * 64 + t];
    cvec[t] = c;
  }
}

// ---------------- fused BN2 reduce + fold into mu/lv weights (1 block) ----------------
__global__ __launch_bounds__(256) void bn_fold_mulv(const float* __restrict__ P, const float* __restrict__ PS,
                                                    int G, int N, const float* __restrict__ g,
                                                    const float* __restrict__ b,
                                                    const float* __restrict__ Wmu, const float* __restrict__ mub,
                                                    const float* __restrict__ Wlv, const float* __restrict__ lvb,
                                                    float* __restrict__ Wmuf, float* __restrict__ cmu,
                                                    float* __restrict__ Wlvf, float* __restrict__ clv) {
  __shared__ float ssv[64], stv[64];
  int t = threadIdx.x;
  if (t < 64) {
    float s = 0.f, ss = 0.f;
    for (int i = 0; i < G; ++i) { s += P[i * 64 + t]; ss += PS[i * 64 + t]; }
    float mean = s / N;
    float var = ss / N - mean * mean;
    float sc = g[t] * rsqrtf(var + 1e-5f);
    ssv[t] = sc;
    stv[t] = b[t] - mean * sc;
  }
  __syncthreads();
  for (int i = t; i < 4096; i += 256) {
    int k = i >> 6;
    Wmuf[i] = ssv[k] * Wmu[i];
    Wlvf[i] = ssv[k] * Wlv[i];
  }
  if (t < 64) {
    float cm = mub[t], cl = lvb[t];
    for (int k = 0; k < 64; ++k) { cm += stv[k] * Wmu[k * 64 + t]; cl += stv[k] * Wlv[k * 64 + t]; }
    cmu[t] = cm; clv[t] = cl;
  }
}

// ---------------- GCN aggregation (bf16 gather, 8-way unrolled) ----------------
__global__ __launch_bounds__(256) void gcn_aggregate_bf(const int* __restrict__ offs, const int* __restrict__ deg,
                                                        const int* __restrict__ csr,
                                                        const unsigned short* __restrict__ xpb2,
                                                        const float* __restrict__ dinv, const float* __restrict__ bias,
                                                        float* __restrict__ g2, int N) {
  int wid = threadIdx.x >> 6, lane = threadIdx.x & 63;
  int n = blockIdx.x * 4 + wid;
  if (n >= N) return;
  int off = offs[n], dg = deg[n];
  float acc = 0.f;
  int k = 0;
  for (; k + 8 <= dg; k += 8) {
    int s_[8];
#pragma unroll
    for (int q = 0; q < 8; ++q) s_[q] = csr[off + k + q];
    float d_[8];
    unsigned short u_[8];
#pragma unroll
    for (int q = 0; q < 8; ++q) d_[q] = dinv[s_[q]];
#pragma unroll
    for (int q = 0; q < 8; ++q) u_[q] = xpb2[(size_t)s_[q] * 64 + lane];
#pragma unroll
    for (int q = 0; q < 8; ++q) acc = fmaf(bf2f(u_[q]), d_[q], acc);
  }
  for (; k + 4 <= dg; k += 4) {
    int sa = csr[off + k], sb = csr[off + k + 1], sc = csr[off + k + 2], sd = csr[off + k + 3];
    float da = dinv[sa], db = dinv[sb], dc = dinv[sc], dd = dinv[sd];
    unsigned short ua = xpb2[(size_t)sa * 64 + lane];
    unsigned short ub = xpb2[(size_t)sb * 64 + lane];
    unsigned short uc = xpb2[(size_t)sc * 64 + lane];
    unsigned short ud = xpb2[(size_t)sd * 64 + lane];
    acc = fmaf(bf2f(ua), da, acc);
    acc = fmaf(bf2f(ub), db, acc);
    acc = fmaf(bf2f(uc), dc, acc);
    acc = fmaf(bf2f(ud), dd, acc);
  }
  for (; k < dg; ++k) {
    int s = csr[off + k];
    acc = fmaf(bf2f(xpb2[(size_t)s * 64 + lane]), dinv[s], acc);
  }
  float v = acc * dinv[n] + bias[lane];
  g2[(size_t)n * 64 + lane] = fmaxf(v, 0.f);
}

// ---------------- fused tail: mu/lv GEMMs + reparam + res GEMM (64x64 tile, K=64) ----------------
__global__ __launch_bounds__(256) void tail_fused(const float* __restrict__ g2,
                                                  const float* __restrict__ Wmuf, const float* __restrict__ cmu,
                                                  const float* __restrict__ Wlvf, const float* __restrict__ clv,
                                                  const float* __restrict__ resW, const float* __restrict__ resb,
                                                  const float* __restrict__ eps,
                                                  float* __restrict__ mu, float* __restrict__ lv,
                                                  unsigned short* __restrict__ rzb, int N) {
  __shared__ float Gs[64][68];
  __shared__ float Wm[64][64];
  __shared__ float Wl[64][64];
  __shared__ float Rw[64][64];
  int t = threadIdx.x;
  int m0 = blockIdx.x * 64;
  int tm = t & 15, tn = t >> 4;

#pragma unroll
  for (int i = 0; i < 4; ++i) {
    int f4 = t + i * 256;
    int row = f4 >> 4;
    int k4 = (f4 & 15) << 2;
    int gr = m0 + row;
    float4 v = make_float4(0.f, 0.f, 0.f, 0.f);
    if (gr < N) v = ld4(g2 + (size_t)gr * 64 + k4);
    Gs[k4 + 0][row] = v.x; Gs[k4 + 1][row] = v.y; Gs[k4 + 2][row] = v.z; Gs[k4 + 3][row] = v.w;
    st4(&Wm[f4 >> 4][k4], ld4(Wmuf + f4 * 4));
    st4(&Wl[f4 >> 4][k4], ld4(Wlvf + f4 * 4));
    st4(&Rw[f4 >> 4][k4], ld4(resW + f4 * 4));
  }
  __syncthreads();

  float am[4][4], al[4][4];
#pragma unroll
  for (int i = 0; i < 4; ++i)
#pragma unroll
    for (int j = 0; j < 4; ++j) { am[i][j] = 0.f; al[i][j] = 0.f; }

#pragma unroll 8
  for (int k = 0; k < 64; ++k) {
    float4 a = ld4(&Gs[k][tm << 2]);
    float4 bm = ld4(&Wm[k][tn << 2]);
    float4 bl = ld4(&Wl[k][tn << 2]);
    float av[4] = {a.x, a.y, a.z, a.w};
    float bmv[4] = {bm.x, bm.y, bm.z, bm.w};
    float blv[4] = {bl.x, bl.y, bl.z, bl.w};
#pragma unroll
    for (int i = 0; i < 4; ++i)
#pragma unroll
      for (int j = 0; j < 4; ++j) {
        am[i][j] = fmaf(av[i], bmv[j], am[i][j]);
        al[i][j] = fmaf(av[i], blv[j], al[i][j]);
      }
  }

  int nb = tn << 2;
  float cm4[4] = {cmu[nb], cmu[nb + 1], cmu[nb + 2], cmu[nb + 3]};
  float cl4[4] = {clv[nb], clv[nb + 1], clv[nb + 2], clv[nb + 3]};
  float zreg[4][4];
#pragma unroll
  for (int i = 0; i < 4; ++i) {
    int gr = m0 + (tm << 2) + i;
    if (gr < N) {
      float4 ep = ld4(eps + (size_t)gr * 64 + nb);
      float epv[4] = {ep.x, ep.y, ep.z, ep.w};
      float muv[4], lvv[4];
#pragma unroll
      for (int j = 0; j < 4; ++j) {
        muv[j] = am[i][j] + cm4[j];
        lvv[j] = al[i][j] + cl4[j];
        zreg[i][j] = fmaf(epv[j], __expf(0.5f * lvv[j]), muv[j]);
      }
      st4(mu + (size_t)gr * 64 + nb, make_float4(muv[0], muv[1], muv[2], muv[3]));
      st4(lv + (size_t)gr * 64 + nb, make_float4(lvv[0], lvv[1], lvv[2], lvv[3]));
    } else {
#pragma unroll
      for (int j = 0; j < 4; ++j) zreg[i][j] = 0.f;
    }
  }

  __syncthreads();
#pragma unroll
  for (int i = 0; i < 4; ++i)
#pragma unroll
    for (int j = 0; j < 4; ++j) Gs[(tn << 2) + j][(tm << 2) + i] = zreg[i][j];
  __syncthreads();

  float ar[4][4];
#pragma unroll
  for (int i = 0; i < 4; ++i)
#pragma unroll
    for (int j = 0; j < 4; ++j) ar[i][j] = 0.f;
#pragma unroll 8
  for (int k = 0; k < 64; ++k) {
    float4 a = ld4(&Gs[k][tm << 2]);
    float4 b = ld4(&Rw[k][tn << 2]);
    float av[4] = {a.x, a.y, a.z, a.w};
    float bv[4] = {b.x, b.y, b.z, b.w};
#pragma unroll
    for (int i = 0; i < 4; ++i)
#pragma unroll
      for (int j = 0; j < 4; ++j) ar[i][j] = fmaf(av[i], bv[j], ar[i][j]);
  }
  float rb4[4] = {resb[nb], resb[nb + 1], resb[nb + 2], resb[nb + 3]};
#pragma unroll
  for (int i = 0; i < 4; ++i) {
    int gr = m0 + (tm << 2) + i;
    if (gr < N) {
      ushort4 o;
      o.x = f2bf(ar[i][0] + rb4[0]);
      o.y = f2bf(ar[i][1] + rb4[1]);
      o.z = f2bf(ar[i][2] + rb4[2]);
      o.w = f2bf(ar[i][3] + rb4[3]);
      *(ushort4*)(rzb + (size_t)gr * 64 + nb) = o;
    }
  }
}

// ---------------- prep gat_W -> transposed bf16 Wtb[col][k] ----------------
__global__ void prep_gatW(const float* __restrict__ W, unsigned short* __restrict__ Wtb) {
  int i = blockIdx.x * blockDim.x + threadIdx.x;
  if (i >= 256 * 256) return;
  int col = i >> 8, k = i & 255;
  Wtb[i] = f2bf(W[k * 256 + col]);
}

// ---------------- prep W1 → bf16 decoder layout [4 kt][256 j][56 kp] (pad 56 => 2-way banks) ----------------
__global__ void prep_W1(const float* __restrict__ W1, unsigned short* __restrict__ W1t) {
  int i = blockIdx.x * blockDim.x + threadIdx.x;
  if (i >= 4 * 256 * 56) return;
  int kt = i / 14336;
  int rem = i - kt * 14336;
  int j = rem / 56;
  int kp = rem - j * 56;
  float v = (kp < 32) ? W1[(size_t)(kt * 32 + kp) * 256 + j] : 0.f;
  W1t[i] = f2bf(v);
}

// ---------------- MFMA decoder (64 edges, 4 waves, B per-kt in LDS, 56-pad B rows) ----------------
// B-read bank math: byte stride/lane = 112 B = 28 words; gcd(28,32)=4 -> 16 lanes start at
// {0,4,...,28}, each ds_read_b128 covers 4 words -> perfect 2-way tiling (free, m136).
__global__ __launch_bounds__(256) void decoder_mfma(const int* __restrict__ ei, int E,
                                                    const unsigned short* __restrict__ rzb,
                                                    const unsigned short* __restrict__ W1t,
                                                    const float* __restrict__ b1, const float* __restrict__ W2,
                                                    const float* __restrict__ b2, float* __restrict__ recon) {
  __shared__ unsigned short Als[64 * 128];   // 16 KB
  __shared__ unsigned short Bls[256 * 56];   // 28 KB
  __shared__ float red[4][64];
  int t = threadIdx.x;
  int wv = t >> 6, l = t & 63;
  int lg = l >> 4, ll = l & 15;
  int e0 = blockIdx.x * 64;

  {
    int e = t >> 2;
    int part = (t >> 1) & 1;
    int half = t & 1;
    int eg = e0 + e;
    if (eg >= E) eg = E - 1;
    int r = (part == 0) ? ei[eg] : ei[E + eg];
    const uint4* gsrc = (const uint4*)(rzb + (size_t)r * 64 + half * 32);
    int bo0 = part * 128 + half * 64;
    int swz = (e & 7) << 4;
#pragma unroll
    for (int c = 0; c < 4; ++c) {
      uint4 v = gsrc[c];
      int bo = bo0 + c * 16;
      *(uint4*)&Als[e * 128 + ((bo ^ swz) >> 1)] = v;
    }
  }

  f32x4 acc[4][4];
#pragma unroll
  for (int a = 0; a < 4; ++a)
#pragma unroll
    for (int b = 0; b < 4; ++b) acc[a][b] = (f32x4){0.f, 0.f, 0.f, 0.f};

  for (int kt = 0; kt < 4; ++kt) {
    __syncthreads();
    {
      // copy 256*56 ushorts = 28672 B = 1792 uint4 (7 x 256)
      const uint4* gsrc = (const uint4*)(W1t + kt * 14336);
      uint4* ldst = (uint4*)Bls;
#pragma unroll
      for (int i = 0; i < 7; ++i) ldst[t + i * 256] = gsrc[t + i * 256];
    }
    __syncthreads();

    bfrag af[4];
#pragma unroll
    for (int fm = 0; fm < 4; ++fm) {
      int e = fm * 16 + ll;
      int bo = kt * 64 + lg * 16;
      af[fm] = *(const bfrag*)&Als[e * 128 + ((bo ^ ((e & 7) << 4)) >> 1)];
    }
#pragma unroll
    for (int fn = 0; fn < 4; ++fn) {
      int j = wv * 64 + fn * 16 + ll;
      bfrag bf = *(const bfrag*)&Bls[j * 56 + lg * 8];
#pragma unroll
      for (int fm = 0; fm < 4; ++fm)
        acc[fm][fn] = __builtin_amdgcn_mfma_f32_16x16x32_bf16(af[fm], bf, acc[fm][fn], 0, 0, 0);
    }
  }

  float bj[4], wj[4];
#pragma unroll
  for (int fn = 0; fn < 4; ++fn) {
    int j = wv * 64 + fn * 16 + ll;
    bj[fn] = b1[j];
    wj[fn] = W2[j];
  }
#pragma unroll
  for (int fm = 0; fm < 4; ++fm) {
    float pr[4] = {0.f, 0.f, 0.f, 0.f};
#pragma unroll
    for (int fn = 0; fn < 4; ++fn) {
#pragma unroll
      for (int r = 0; r < 4; ++r)
        pr[r] = fmaf(fmaxf(acc[fm][fn][r] + bj[fn], 0.f), wj[fn], pr[r]);
    }
#pragma unroll
    for (int m = 8; m >= 1; m >>= 1) {
#pragma unroll
      for (int r = 0; r < 4; ++r) pr[r] += __shfl_xor(pr[r], m);
    }
    if (ll == 0) {
#pragma unroll
      for (int r = 0; r < 4; ++r) red[wv][fm * 16 + lg * 4 + r] = pr[r];
    }
  }
  __syncthreads();
  if (t < 64) {
    int eg = e0 + t;
    if (eg < E) recon[eg] = red[0][t] + red[1][t] + red[2][t] + red[3][t] + b2[0];
  }
}

extern "C" void kernel_launch(void* const* d_in, const int* in_sizes, int n_in,
                              void* d_out, int out_size, void* d_ws, size_t ws_size,
                              hipStream_t stream) {
  const float* x = (const float*)d_in[0];
  const int* ei = (const int*)d_in[1];
  const float* gat_W = (const float*)d_in[2];
  const float* att_src = (const float*)d_in[3];
  const float* att_dst = (const float*)d_in[4];
  const float* gat_bias = (const float*)d_in[5];
  const float* bn1_g = (const float*)d_in[6];
  const float* bn1_b = (const float*)d_in[7];
  const float* gcn_W = (const float*)d_in[8];
  const float* gcn_bias = (const float*)d_in[9];
  const float* bn2_g = (const float*)d_in[10];
  const float* bn2_b = (const float*)d_in[11];
  const float* mu_W = (const float*)d_in[12];
  const float* mu_b = (const float*)d_in[13];
  const float* lv_W = (const float*)d_in[14];
  const float* lv_b = (const float*)d_in[15];
  const float* res_W = (const float*)d_in[16];
  const float* res_b = (const float*)d_in[17];
  const float* dec_W1 = (const float*)d_in[18];
  const float* dec_b1 = (const float*)d_in[19];
  const float* dec_W2 = (const float*)d_in[20];
  const float* dec_b2 = (const float*)d_in[21];
  const float* eps = (const float*)d_in[22];

  int N = in_sizes[0] / DIN;   // 50000
  int E = in_sizes[1] / 2;     // 800000
  int Et = E + N;
  int NB = (N + 255) / 256;    // scan chunks (<= 256)

  float* ws = (float*)d_ws;
  size_t off = 0;
  float* xp = ws; off += (size_t)N * 256;
  unsigned short* xpb = (unsigned short*)xp;    // bf16 xp rows, stride 512 ushorts
  unsigned short* xpb2 = (unsigned short*)xp;   // bf16 xp2 [N,64] (xpb dead by then)
  float* g2 = xp + (size_t)N * 64;
  float* rz = xp + (size_t)N * 192;
  unsigned short* rzb = (unsigned short*)rz;    // bf16 res_z [N,64]
  float* h1 = ws + off; off += (size_t)N * 128;
  float* a_src = ws + off; off += (size_t)2 * N;
  float* a_dst = ws + off; off += (size_t)2 * N;
  float* dinv = ws + off; off += N;
  float* P = ws + off; off += 128 * 128;
  float* PS = ws + off; off += 128 * 128;
  float* W2f = ws + off; off += 128 * 64;
  float* c2 = ws + off; off += 64;
  float* Wmuf = ws + off; off += 64 * 64;
  float* cmu = ws + off; off += 64;
  float* Wlvf = ws + off; off += 64 * 64;
  float* clv = ws + off; off += 64;
  unsigned short* W1t = (unsigned short*)(ws + off); off += 28672;   // 4*256*56 bf16
  unsigned short* Wtb = (unsigned short*)(ws + off); off += 32768;   // 256*256 bf16
  int* deg = (int*)(ws + off); off += N;
  int* offs = (int*)(ws + off); off += N;
  int* cursor = (int*)(ws + off); off += N;
  int* bsum = (int*)(ws + off); off += 256;
  int* csr = (int*)(ws + off); off += Et;

  float* recon = (float*)d_out;
  float* mu = recon + E;
  float* lv = mu + (size_t)N * LAT;

  // 0. weight preps + zero attn-score accumulators (a_src/a_dst contiguous)
  prep_W1<<<(4 * 256 * 56 + 255) / 256, 256, 0, stream>>>(dec_W1, W1t);
  prep_gatW<<<(256 * 256 + 255) / 256, 256, 0, stream>>>(gat_W, Wtb);
  hipMemsetAsync(a_src, 0, (size_t)4 * N * sizeof(float), stream);

  // 1. xp = x @ gat_W via MFMA; attention scores fused (atomic partials)
  dim3 gX(4, (N + 63) / 64);
  gemm_xp_mfma<<<gX, 256, 0, stream>>>(x, Wtb, att_src, att_dst, xpb, a_src, a_dst, N);

  // 2. CSR build (parallel 3-phase scan)
  hipMemsetAsync(deg, 0, (size_t)N * sizeof(int), stream);
  deg_count<<<(Et + 255) / 256, 256, 0, stream>>>(ei, E, Et, deg);
  bsum_kernel<<<NB, 256, 0, stream>>>(deg, N, bsum);
  bscan_kernel<<<1, 256, 0, stream>>>(bsum, NB);
  scan_apply<<<NB, 256, 0, stream>>>(deg, bsum, N, offs, cursor, dinv);
  csr_fill<<<(Et + 255) / 256, 256, 0, stream>>>(ei, E, Et, cursor, csr);

  // 3. fused GAT softmax + aggregation (8-way MLP unroll)
  gat_fused<<<(N + 3) / 4, 256, 0, stream>>>(offs, deg, csr, a_src, a_dst, xpb, gat_bias, h1, N);

  // 4. BN1 reduce+fold fused; xp2 (bf16) = h1 @ W2f + c2
  bn_stats<128><<<128, 256, 0, stream>>>(h1, N, P, PS);
  bn_fold_gcn<<<1, 256, 0, stream>>>(P, PS, 128, N, bn1_g, bn1_b, gcn_W, W2f, c2);
  dim3 gB((N + 63) / 64, 1);
  gemm64b<<<gB, 256, 0, stream>>>(h1, W2f, c2, xpb2, N, 64, 128);

  // 5. GCN aggregation (bf16 gather, 8-way MLP unroll)
  gcn_aggregate_bf<<<(N + 3) / 4, 256, 0, stream>>>(offs, deg, csr, xpb2, dinv, gcn_bias, g2, N);

  // 6. BN2 reduce+fold; fused tail (mu, lv, reparam, res GEMM in one kernel)
  bn_stats<64><<<128, 256, 0, stream>>>(g2, N, P, PS);
  bn_fold_mulv<<<1, 256, 0, stream>>>(P, PS, 128, N, bn2_g, bn2_b, mu_W, mu_b, lv_W, lv_b,
                                      Wmuf, cmu, Wlvf, clv);
  tail_fused<<<(N + 63) / 64, 256, 0, stream>>>(g2, Wmuf, cmu, Wlvf, clv, res_W, res_b, eps,
                                                mu, lv, rzb, N);

  // 7. MFMA decoder (56-pad B rows: bank-conflict-free reads)
  decoder_mfma<<<(E + 63) / 64, 256, 0, stream>>>(ei, E, rzb, W1t, dec_b1, dec_W2, dec_b2, recon);
}

// Round 14
// 565.374 us; speedup vs baseline: 1.0171x; 1.0080x over previous
//
#include <hip/hip_runtime.h>
#include <math.h>

constexpr int DIN = 256;
constexpr int HID = 128;
constexpr int LAT = 64;

typedef short bfrag __attribute__((ext_vector_type(8)));   // 8 bf16 (4 VGPRs)
typedef float f32x4 __attribute__((ext_vector_type(4)));

__device__ __forceinline__ float4 ld4(const float* p) { return *reinterpret_cast<const float4*>(p); }
__device__ __forceinline__ void st4(float* p, float4 v) { *reinterpret_cast<float4*>(p) = v; }

__device__ __forceinline__ unsigned short f2bf(float f) {
  unsigned int u = __float_as_uint(f);
  unsigned int r = (u + 0x7FFFu + ((u >> 16) & 1u)) >> 16;  // RNE
  return (unsigned short)r;
}

__device__ __forceinline__ float bf2f(unsigned short u) {
  return __uint_as_float(((unsigned int)u) << 16);
}

// ---------------- f32 GEMM with bf16 output: Cb[M,N](bf16) = A[M,K] @ B[K,N] + crow ----------------
__global__ __launch_bounds__(256) void gemm64b(const float* __restrict__ A, const float* __restrict__ B,
                                               const float* __restrict__ crow, unsigned short* __restrict__ Cb,
                                               int M, int N, int K) {
  __shared__ float As[32][68];
  __shared__ float Bs[32][68];
  int t = threadIdx.x;
  int m0 = blockIdx.x * 64, n0 = blockIdx.y * 64;
  int tm = t & 15, tn = t >> 4;
  float acc[4][4];
#pragma unroll
  for (int i = 0; i < 4; i++)
#pragma unroll
    for (int j = 0; j < 4; j++) acc[i][j] = 0.f;

  for (int kt = 0; kt < K; kt += 32) {
#pragma unroll
    for (int i = 0; i < 2; ++i) {
      int f4 = t + i * 256;
      int m = f4 >> 3;
      int k4 = (f4 & 7) << 2;
      int gm = m0 + m;
      float4 v = make_float4(0.f, 0.f, 0.f, 0.f);
      if (gm < M) v = ld4(A + (size_t)gm * K + kt + k4);
      As[k4 + 0][m] = v.x; As[k4 + 1][m] = v.y; As[k4 + 2][m] = v.z; As[k4 + 3][m] = v.w;
    }
#pragma unroll
    for (int i = 0; i < 2; ++i) {
      int f4 = t + i * 256;
      int k = f4 >> 4;
      int n4 = (f4 & 15) << 2;
      float4 v = ld4(B + (size_t)(kt + k) * N + n0 + n4);
      st4(&Bs[k][n4], v);
    }
    __syncthreads();
#pragma unroll
    for (int k = 0; k < 32; ++k) {
      float4 a = ld4(&As[k][tm << 2]);
      float4 b = ld4(&Bs[k][tn << 2]);
      float av[4] = {a.x, a.y, a.z, a.w};
      float bv[4] = {b.x, b.y, b.z, b.w};
#pragma unroll
      for (int i = 0; i < 4; i++)
#pragma unroll
        for (int j = 0; j < 4; j++) acc[i][j] = fmaf(av[i], bv[j], acc[i][j]);
    }
    __syncthreads();
  }
#pragma unroll
  for (int i = 0; i < 4; ++i) {
    int gm = m0 + (tm << 2) + i;
    if (gm < M) {
      int nb = n0 + (tn << 2);
      ushort4 o;
      o.x = f2bf(acc[i][0] + crow[nb]);
      o.y = f2bf(acc[i][1] + crow[nb + 1]);
      o.z = f2bf(acc[i][2] + crow[nb + 2]);
      o.w = f2bf(acc[i][3] + crow[nb + 3]);
      *(ushort4*)(Cb + (size_t)gm * N + nb) = o;
    }
  }
}

// ---------------- MFMA GEMM: xpb = x(f32) @ Wtb^T, bf16 out; attn scores fused in epilogue ----------------
__global__ __launch_bounds__(256) void gemm_xp_mfma(const float* __restrict__ xf,
                                                    const unsigned short* __restrict__ Wtb,
                                                    const float* __restrict__ att_src,
                                                    const float* __restrict__ att_dst,
                                                    unsigned short* __restrict__ xpb,
                                                    float* __restrict__ a_src, float* __restrict__ a_dst, int M) {
  __shared__ unsigned short Als[64 * 256];
  __shared__ unsigned short Bls[64 * 256];
  int t = threadIdx.x;
  int wv = t >> 6, l = t & 63, lg = l >> 4, ll = l & 15;
  int cg = blockIdx.x;
  int rt = blockIdx.y;

  {
    int row = t >> 2, seg = t & 3;
    int gr = min(rt * 64 + row, M - 1);
    const float4* src = (const float4*)(xf + (size_t)gr * 256 + seg * 64);
    int swz = (row & 7) << 4;
#pragma unroll
    for (int c = 0; c < 8; ++c) {
      float4 a = src[2 * c], b = src[2 * c + 1];
      uint4 v;
      v.x = (unsigned)f2bf(a.x) | ((unsigned)f2bf(a.y) << 16);
      v.y = (unsigned)f2bf(a.z) | ((unsigned)f2bf(a.w) << 16);
      v.z = (unsigned)f2bf(b.x) | ((unsigned)f2bf(b.y) << 16);
      v.w = (unsigned)f2bf(b.z) | ((unsigned)f2bf(b.w) << 16);
      int bo = seg * 128 + c * 16;
      *(uint4*)((char*)Als + row * 512 + (bo ^ swz)) = v;
    }
  }
  {
    int col = t >> 2, seg = t & 3;
    const uint4* src = (const uint4*)(Wtb + (size_t)(cg * 64 + col) * 256 + seg * 64);
    int swz = (col & 7) << 4;
#pragma unroll
    for (int c = 0; c < 8; ++c) {
      int bo = seg * 128 + c * 16;
      *(uint4*)((char*)Bls + col * 512 + (bo ^ swz)) = src[c];
    }
  }
  __syncthreads();

  f32x4 acc[4];
#pragma unroll
  for (int i = 0; i < 4; ++i) acc[i] = (f32x4){0.f, 0.f, 0.f, 0.f};

#pragma unroll
  for (int kt = 0; kt < 8; ++kt) {
    int ar = wv * 16 + ll;
    bfrag af = *(const bfrag*)((char*)Als + ar * 512 + ((kt * 64 + lg * 16) ^ ((ar & 7) << 4)));
#pragma unroll
    for (int fn = 0; fn < 4; ++fn) {
      int bc = fn * 16 + ll;
      bfrag bf = *(const bfrag*)((char*)Bls + bc * 512 + ((kt * 64 + lg * 16) ^ ((bc & 7) << 4)));
      acc[fn] = __builtin_amdgcn_mfma_f32_16x16x32_bf16(af, bf, acc[fn], 0, 0, 0);
    }
  }

#pragma unroll
  for (int fn = 0; fn < 4; ++fn) {
#pragma unroll
    for (int r = 0; r < 4; ++r) {
      int row = rt * 64 + wv * 16 + lg * 4 + r;
      if (row < M) xpb[(size_t)row * 512 + cg * 64 + fn * 16 + ll] = f2bf(acc[fn][r]);
    }
  }

  // ---- fused attention-score partials ----
  int h = cg >> 1;
  int c0 = (cg & 1) * 64;
  float asv[4], adv[4];
#pragma unroll
  for (int fn = 0; fn < 4; ++fn) {
    asv[fn] = att_src[h * 128 + c0 + fn * 16 + ll];
    adv[fn] = att_dst[h * 128 + c0 + fn * 16 + ll];
  }
  float ps[4] = {0.f, 0.f, 0.f, 0.f}, pd[4] = {0.f, 0.f, 0.f, 0.f};
#pragma unroll
  for (int fn = 0; fn < 4; ++fn)
#pragma unroll
    for (int r = 0; r < 4; ++r) {
      ps[r] = fmaf(acc[fn][r], asv[fn], ps[r]);
      pd[r] = fmaf(acc[fn][r], adv[fn], pd[r]);
    }
#pragma unroll
  for (int m = 8; m >= 1; m >>= 1) {
#pragma unroll
    for (int r = 0; r < 4; ++r) { ps[r] += __shfl_xor(ps[r], m); pd[r] += __shfl_xor(pd[r], m); }
  }
  if (ll == 0) {
#pragma unroll
    for (int r = 0; r < 4; ++r) {
      int row = rt * 64 + wv * 16 + lg * 4 + r;
      if (row < M) {
        atomicAdd(&a_src[row * 2 + h], ps[r]);
        atomicAdd(&a_dst[row * 2 + h], pd[r]);
      }
    }
  }
}

// ---------------- CSR build ----------------
__global__ void deg_count(const int* __restrict__ ei, int E, int Et, int* __restrict__ deg) {
  int i = blockIdx.x * blockDim.x + threadIdx.x;
  if (i >= Et) return;
  int d = (i < E) ? ei[E + i] : (i - E);
  atomicAdd(&deg[d], 1);
}

__global__ __launch_bounds__(256) void bsum_kernel(const int* __restrict__ deg, int N, int* __restrict__ bsum) {
  int t = threadIdx.x;
  int i = blockIdx.x * 256 + t;
  int v = (i < N) ? deg[i] : 0;
#pragma unroll
  for (int m = 32; m >= 1; m >>= 1) v += __shfl_xor(v, m);
  __shared__ int sh[4];
  if ((t & 63) == 0) sh[t >> 6] = v;
  __syncthreads();
  if (t == 0) bsum[blockIdx.x] = sh[0] + sh[1] + sh[2] + sh[3];
}

__global__ __launch_bounds__(256) void bscan_kernel(int* __restrict__ bsum, int B) {
  __shared__ int sh[256];
  int t = threadIdx.x;
  int v = (t < B) ? bsum[t] : 0;
  sh[t] = v;
  __syncthreads();
  for (int d = 1; d < 256; d <<= 1) {
    int x = (t >= d) ? sh[t - d] : 0;
    __syncthreads();
    sh[t] += x;
    __syncthreads();
  }
  if (t < B) bsum[t] = sh[t] - v;
}

__global__ __launch_bounds__(256) void scan_apply(const int* __restrict__ deg, const int* __restrict__ bsum, int N,
                                                  int* __restrict__ offs, int* __restrict__ cursor,
                                                  float* __restrict__ dinv) {
  int t = threadIdx.x;
  int i = blockIdx.x * 256 + t;
  int v = (i < N) ? deg[i] : 0;
  __shared__ int sh[256];
  sh[t] = v;
  __syncthreads();
  for (int d = 1; d < 256; d <<= 1) {
    int x = (t >= d) ? sh[t - d] : 0;
    __syncthreads();
    sh[t] += x;
    __syncthreads();
  }
  if (i < N) {
    int off = bsum[blockIdx.x] + sh[t] - v;
    offs[i] = off;
    cursor[i] = off;
    dinv[i] = rsqrtf((float)v);   // deg >= 1 (self-loop)
  }
}

__global__ void csr_fill(const int* __restrict__ ei, int E, int Et, int* __restrict__ cursor, int* __restrict__ csr) {
  int i = blockIdx.x * blockDim.x + threadIdx.x;
  if (i >= Et) return;
  int s, d;
  if (i < E) { s = ei[i]; d = ei[E + i]; } else { s = i - E; d = i - E; }
  int pos = atomicAdd(&cursor[d], 1);
  csr[pos] = s;
}

// ---------------- FUSED GAT, no-max softmax, 8-way unrolled gather (wave per node) ----------------
__global__ __launch_bounds__(256) void gat_fused(const int* __restrict__ offs, const int* __restrict__ deg,
                                                 const int* __restrict__ csr, const float* __restrict__ a_src,
                                                 const float* __restrict__ a_dst,
                                                 const unsigned short* __restrict__ xpb,
                                                 const float* __restrict__ bias,
                                                 float* __restrict__ h1, int N) {
  int wid = threadIdx.x >> 6, lane = threadIdx.x & 63;
  int n = blockIdx.x * 4 + wid;
  if (n >= N) return;
  int off = offs[n], dg = deg[n];
  float ad0 = a_dst[n * 2], ad1 = a_dst[n * 2 + 1];
  const float2* as2 = (const float2*)a_src;

  float4 acc = make_float4(0.f, 0.f, 0.f, 0.f);
  float s0 = 0.f, s1 = 0.f;
  bool h0 = lane < 32;

#define GAT_STEP(aa, uu)                                         \
  {                                                              \
    float e0 = (aa).x + ad0; e0 = e0 >= 0.f ? e0 : 0.2f * e0;    \
    float e1 = (aa).y + ad1; e1 = e1 >= 0.f ? e1 : 0.2f * e1;    \
    float x0 = __expf(e0), x1 = __expf(e1);                      \
    s0 += x0; s1 += x1;                                          \
    float xa = h0 ? x0 : x1;                                     \
    acc.x = fmaf(bf2f((uu).x), xa, acc.x);                       \
    acc.y = fmaf(bf2f((uu).y), xa, acc.y);                       \
    acc.z = fmaf(bf2f((uu).z), xa, acc.z);                       \
    acc.w = fmaf(bf2f((uu).w), xa, acc.w);                       \
  }

  int k = 0;
  for (; k + 8 <= dg; k += 8) {
    int s_[8];
#pragma unroll
    for (int q = 0; q < 8; ++q) s_[q] = csr[off + k + q];
    float2 a_[8];
    ushort4 u_[8];
#pragma unroll
    for (int q = 0; q < 8; ++q) a_[q] = as2[s_[q]];
#pragma unroll
    for (int q = 0; q < 8; ++q) u_[q] = ((const ushort4*)(xpb + (size_t)s_[q] * 512))[lane];
#pragma unroll
    for (int q = 0; q < 8; ++q) GAT_STEP(a_[q], u_[q]);
  }
  for (; k + 4 <= dg; k += 4) {
    int sa = csr[off + k], sb = csr[off + k + 1], sc = csr[off + k + 2], sd = csr[off + k + 3];
    float2 aa = as2[sa], ab = as2[sb], ac = as2[sc], ad = as2[sd];
    ushort4 ua = ((const ushort4*)(xpb + (size_t)sa * 512))[lane];
    ushort4 ub = ((const ushort4*)(xpb + (size_t)sb * 512))[lane];
    ushort4 uc = ((const ushort4*)(xpb + (size_t)sc * 512))[lane];
    ushort4 ud = ((const ushort4*)(xpb + (size_t)sd * 512))[lane];
    GAT_STEP(aa, ua); GAT_STEP(ab, ub); GAT_STEP(ac, uc); GAT_STEP(ad, ud);
  }
  for (; k < dg; ++k) {
    int s = csr[off + k];
    float2 a = as2[s];
    ushort4 u = ((const ushort4*)(xpb + (size_t)s * 512))[lane];
    GAT_STEP(a, u);
  }
#undef GAT_STEP

  float r = h0 ? (1.f / s0) : (1.f / s1);
  acc.x *= r; acc.y *= r; acc.z *= r; acc.w *= r;

  float ox = __shfl_down(acc.x, 32);
  float oy = __shfl_down(acc.y, 32);
  float oz = __shfl_down(acc.z, 32);
  float ow = __shfl_down(acc.w, 32);
  if (h0) {
    int f4 = lane << 2;
    float4 b = ld4(bias + f4);
    float4 o;
    o.x = fmaxf(0.f, (acc.x + ox) * 0.5f + b.x);
    o.y = fmaxf(0.f, (acc.y + oy) * 0.5f + b.y);
    o.z = fmaxf(0.f, (acc.z + oz) * 0.5f + b.z);
    o.w = fmaxf(0.f, (acc.w + ow) * 0.5f + b.w);
    st4(h1 + (size_t)n * 128 + f4, o);
  }
}

// ---------------- BatchNorm stats ----------------
template <int C>
__global__ __launch_bounds__(256) void bn_stats(const float* __restrict__ h, int N, float* __restrict__ P,
                                                float* __restrict__ PS) {
  constexpr int R = 256 / C;
  __shared__ float sh[256], sh2[256];
  int t = threadIdx.x;
  int c = t % C, r = t / C;
  float s = 0.f, ss = 0.f;
  for (int n = blockIdx.x * R + r; n < N; n += gridDim.x * R) {
    float v = h[(size_t)n * C + c];
    s += v; ss += v * v;
  }
  sh[t] = s; sh2[t] = ss;
  __syncthreads();
  if (r == 0) {
#pragma unroll
    for (int i = 1; i < R; ++i) { s += sh[i * C + c]; ss += sh2[i * C + c]; }
    P[blockIdx.x * C + c] = s;
    PS[blockIdx.x * C + c] = ss;
  }
}

// ---------------- fused BN1 reduce + fold into GCN weights (1 block) ----------------
__global__ __launch_bounds__(256) void bn_fold_gcn(const float* __restrict__ P, const float* __restrict__ PS,
                                                   int G, int N, const float* __restrict__ g,
                                                   const float* __restrict__ b, const float* __restrict__ W,
                                                   float* __restrict__ Wf, float* __restrict__ cvec) {
  __shared__ float ssv[128], stv[128];
  int t = threadIdx.x;
  if (t < 128) {
    float s = 0.f, ss = 0.f;
    for (int i = 0; i < G; ++i) { s += P[i * 128 + t]; ss += PS[i * 128 + t]; }
    float mean = s / N;
    float var = ss / N - mean * mean;
    float sc = g[t] * rsqrtf(var + 1e-5f);
    ssv[t] = sc;
    stv[t] = b[t] - mean * sc;
  }
  __syncthreads();
  for (int i = t; i < 128 * 64; i += 256) {
    int k = i >> 6;
    Wf[i] = ssv[k] * W[i];
  }
  if (t < 64) {
    float c = 0.f;
    for (int k = 0; k < 128; ++k) c += stv[k] * W[k * 64 + t];
    cvec[t] = c;
  }
}

// ---------------- fused BN2 reduce + fold into mu/lv weights (1 block) ----------------
__global__ __launch_bounds__(256) void bn_fold_mulv(const float* __restrict__ P, const float* __restrict__ PS,
                                                    int G, int N, const float* __restrict__ g,
                                                    const float* __restrict__ b,
                                                    const float* __restrict__ Wmu, const float* __restrict__ mub,
                                                    const float* __restrict__ Wlv, const float* __restrict__ lvb,
                                                    float* __restrict__ Wmuf, float* __restrict__ cmu,
                                                    float* __restrict__ Wlvf, float* __restrict__ clv) {
  __shared__ float ssv[64], stv[64];
  int t = threadIdx.x;
  if (t < 64) {
    float s = 0.f, ss = 0.f;
    for (int i = 0; i < G; ++i) { s += P[i * 64 + t]; ss += PS[i * 64 + t]; }
    float mean = s / N;
    float var = ss / N - mean * mean;
    float sc = g[t] * rsqrtf(var + 1e-5f);
    ssv[t] = sc;
    stv[t] = b[t] - mean * sc;
  }
  __syncthreads();
  for (int i = t; i < 4096; i += 256) {
    int k = i >> 6;
    Wmuf[i] = ssv[k] * Wmu[i];
    Wlvf[i] = ssv[k] * Wlv[i];
  }
  if (t < 64) {
    float cm = mub[t], cl = lvb[t];
    for (int k = 0; k < 64; ++k) { cm += stv[k] * Wmu[k * 64 + t]; cl += stv[k] * Wlv[k * 64 + t]; }
    cmu[t] = cm; clv[t] = cl;
  }
}

// ---------------- GCN aggregation (bf16 gather, 8-way unrolled) ----------------
__global__ __launch_bounds__(256) void gcn_aggregate_bf(const int* __restrict__ offs, const int* __restrict__ deg,
                                                        const int* __restrict__ csr,
                                                        const unsigned short* __restrict__ xpb2,
                                                        const float* __restrict__ dinv, const float* __restrict__ bias,
                                                        float* __restrict__ g2, int N) {
  int wid = threadIdx.x >> 6, lane = threadIdx.x & 63;
  int n = blockIdx.x * 4 + wid;
  if (n >= N) return;
  int off = offs[n], dg = deg[n];
  float acc = 0.f;
  int k = 0;
  for (; k + 8 <= dg; k += 8) {
    int s_[8];
#pragma unroll
    for (int q = 0; q < 8; ++q) s_[q] = csr[off + k + q];
    float d_[8];
    unsigned short u_[8];
#pragma unroll
    for (int q = 0; q < 8; ++q) d_[q] = dinv[s_[q]];
#pragma unroll
    for (int q = 0; q < 8; ++q) u_[q] = xpb2[(size_t)s_[q] * 64 + lane];
#pragma unroll
    for (int q = 0; q < 8; ++q) acc = fmaf(bf2f(u_[q]), d_[q], acc);
  }
  for (; k + 4 <= dg; k += 4) {
    int sa = csr[off + k], sb = csr[off + k + 1], sc = csr[off + k + 2], sd = csr[off + k + 3];
    float da = dinv[sa], db = dinv[sb], dc = dinv[sc], dd = dinv[sd];
    unsigned short ua = xpb2[(size_t)sa * 64 + lane];
    unsigned short ub = xpb2[(size_t)sb * 64 + lane];
    unsigned short uc = xpb2[(size_t)sc * 64 + lane];
    unsigned short ud = xpb2[(size_t)sd * 64 + lane];
    acc = fmaf(bf2f(ua), da, acc);
    acc = fmaf(bf2f(ub), db, acc);
    acc = fmaf(bf2f(uc), dc, acc);
    acc = fmaf(bf2f(ud), dd, acc);
  }
  for (; k < dg; ++k) {
    int s = csr[off + k];
    acc = fmaf(bf2f(xpb2[(size_t)s * 64 + lane]), dinv[s], acc);
  }
  float v = acc * dinv[n] + bias[lane];
  g2[(size_t)n * 64 + lane] = fmaxf(v, 0.f);
}

// ---------------- fused tail: mu/lv GEMMs + reparam + res GEMM (64x64 tile, K=64) ----------------
__global__ __launch_bounds__(256) void tail_fused(const float* __restrict__ g2,
                                                  const float* __restrict__ Wmuf, const float* __restrict__ cmu,
                                                  const float* __restrict__ Wlvf, const float* __restrict__ clv,
                                                  const float* __restrict__ resW, const float* __restrict__ resb,
                                                  const float* __restrict__ eps,
                                                  float* __restrict__ mu, float* __restrict__ lv,
                                                  unsigned short* __restrict__ rzb, int N) {
  __shared__ float Gs[64][68];
  __shared__ float Wm[64][64];
  __shared__ float Wl[64][64];
  __shared__ float Rw[64][64];
  int t = threadIdx.x;
  int m0 = blockIdx.x * 64;
  int tm = t & 15, tn = t >> 4;

#pragma unroll
  for (int i = 0; i < 4; ++i) {
    int f4 = t + i * 256;
    int row = f4 >> 4;
    int k4 = (f4 & 15) << 2;
    int gr = m0 + row;
    float4 v = make_float4(0.f, 0.f, 0.f, 0.f);
    if (gr < N) v = ld4(g2 + (size_t)gr * 64 + k4);
    Gs[k4 + 0][row] = v.x; Gs[k4 + 1][row] = v.y; Gs[k4 + 2][row] = v.z; Gs[k4 + 3][row] = v.w;
    st4(&Wm[f4 >> 4][k4], ld4(Wmuf + f4 * 4));
    st4(&Wl[f4 >> 4][k4], ld4(Wlvf + f4 * 4));
    st4(&Rw[f4 >> 4][k4], ld4(resW + f4 * 4));
  }
  __syncthreads();

  float am[4][4], al[4][4];
#pragma unroll
  for (int i = 0; i < 4; ++i)
#pragma unroll
    for (int j = 0; j < 4; ++j) { am[i][j] = 0.f; al[i][j] = 0.f; }

#pragma unroll 8
  for (int k = 0; k < 64; ++k) {
    float4 a = ld4(&Gs[k][tm << 2]);
    float4 bm = ld4(&Wm[k][tn << 2]);
    float4 bl = ld4(&Wl[k][tn << 2]);
    float av[4] = {a.x, a.y, a.z, a.w};
    float bmv[4] = {bm.x, bm.y, bm.z, bm.w};
    float blv[4] = {bl.x, bl.y, bl.z, bl.w};
#pragma unroll
    for (int i = 0; i < 4; ++i)
#pragma unroll
      for (int j = 0; j < 4; ++j) {
        am[i][j] = fmaf(av[i], bmv[j], am[i][j]);
        al[i][j] = fmaf(av[i], blv[j], al[i][j]);
      }
  }

  int nb = tn << 2;
  float cm4[4] = {cmu[nb], cmu[nb + 1], cmu[nb + 2], cmu[nb + 3]};
  float cl4[4] = {clv[nb], clv[nb + 1], clv[nb + 2], clv[nb + 3]};
  float zreg[4][4];
#pragma unroll
  for (int i = 0; i < 4; ++i) {
    int gr = m0 + (tm << 2) + i;
    if (gr < N) {
      float4 ep = ld4(eps + (size_t)gr * 64 + nb);
      float epv[4] = {ep.x, ep.y, ep.z, ep.w};
      float muv[4], lvv[4];
#pragma unroll
      for (int j = 0; j < 4; ++j) {
        muv[j] = am[i][j] + cm4[j];
        lvv[j] = al[i][j] + cl4[j];
        zreg[i][j] = fmaf(epv[j], __expf(0.5f * lvv[j]), muv[j]);
      }
      st4(mu + (size_t)gr * 64 + nb, make_float4(muv[0], muv[1], muv[2], muv[3]));
      st4(lv + (size_t)gr * 64 + nb, make_float4(lvv[0], lvv[1], lvv[2], lvv[3]));
    } else {
#pragma unroll
      for (int j = 0; j < 4; ++j) zreg[i][j] = 0.f;
    }
  }

  __syncthreads();
#pragma unroll
  for (int i = 0; i < 4; ++i)
#pragma unroll
    for (int j = 0; j < 4; ++j) Gs[(tn << 2) + j][(tm << 2) + i] = zreg[i][j];
  __syncthreads();

  float ar[4][4];
#pragma unroll
  for (int i = 0; i < 4; ++i)
#pragma unroll
    for (int j = 0; j < 4; ++j) ar[i][j] = 0.f;
#pragma unroll 8
  for (int k = 0; k < 64; ++k) {
    float4 a = ld4(&Gs[k][tm << 2]);
    float4 b = ld4(&Rw[k][tn << 2]);
    float av[4] = {a.x, a.y, a.z, a.w};
    float bv[4] = {b.x, b.y, b.z, b.w};
#pragma unroll
    for (int i = 0; i < 4; ++i)
#pragma unroll
      for (int j = 0; j < 4; ++j) ar[i][j] = fmaf(av[i], bv[j], ar[i][j]);
  }
  float rb4[4] = {resb[nb], resb[nb + 1], resb[nb + 2], resb[nb + 3]};
#pragma unroll
  for (int i = 0; i < 4; ++i) {
    int gr = m0 + (tm << 2) + i;
    if (gr < N) {
      ushort4 o;
      o.x = f2bf(ar[i][0] + rb4[0]);
      o.y = f2bf(ar[i][1] + rb4[1]);
      o.z = f2bf(ar[i][2] + rb4[2]);
      o.w = f2bf(ar[i][3] + rb4[3]);
      *(ushort4*)(rzb + (size_t)gr * 64 + nb) = o;
    }
  }
}

// ---------------- prep gat_W -> transposed bf16 Wtb[col][k] ----------------
__global__ void prep_gatW(const float* __restrict__ W, unsigned short* __restrict__ Wtb) {
  int i = blockIdx.x * blockDim.x + threadIdx.x;
  if (i >= 256 * 256) return;
  int col = i >> 8, k = i & 255;
  Wtb[i] = f2bf(W[k * 256 + col]);
}

// ---------------- prep W1 → bf16 decoder layout [4 kt][256 j][40 kp] (padded) ----------------
__global__ void prep_W1(const float* __restrict__ W1, unsigned short* __restrict__ W1t) {
  int i = blockIdx.x * blockDim.x + threadIdx.x;
  if (i >= 4 * 256 * 40) return;
  int kt = i / 10240;
  int rem = i - kt * 10240;
  int j = rem / 40;
  int kp = rem - j * 40;
  float v = (kp < 32) ? W1[(size_t)(kt * 32 + kp) * 256 + j] : 0.f;
  W1t[i] = f2bf(v);
}

// ---------------- MFMA decoder (64 edges, 4 waves, B per-kt in LDS, 40-pad; setprio on MFMA) ----------------
__global__ __launch_bounds__(256) void decoder_mfma(const int* __restrict__ ei, int E,
                                                    const unsigned short* __restrict__ rzb,
                                                    const unsigned short* __restrict__ W1t,
                                                    const float* __restrict__ b1, const float* __restrict__ W2,
                                                    const float* __restrict__ b2, float* __restrict__ recon) {
  __shared__ unsigned short Als[64 * 128];   // 16 KB
  __shared__ unsigned short Bls[256 * 40];   // 20 KB
  __shared__ float red[4][64];
  int t = threadIdx.x;
  int wv = t >> 6, l = t & 63;
  int lg = l >> 4, ll = l & 15;
  int e0 = blockIdx.x * 64;

  {
    int e = t >> 2;
    int part = (t >> 1) & 1;
    int half = t & 1;
    int eg = e0 + e;
    if (eg >= E) eg = E - 1;
    int r = (part == 0) ? ei[eg] : ei[E + eg];
    const uint4* gsrc = (const uint4*)(rzb + (size_t)r * 64 + half * 32);
    int bo0 = part * 128 + half * 64;
    int swz = (e & 7) << 4;
#pragma unroll
    for (int c = 0; c < 4; ++c) {
      uint4 v = gsrc[c];
      int bo = bo0 + c * 16;
      *(uint4*)&Als[e * 128 + ((bo ^ swz) >> 1)] = v;
    }
  }

  f32x4 acc[4][4];
#pragma unroll
  for (int a = 0; a < 4; ++a)
#pragma unroll
    for (int b = 0; b < 4; ++b) acc[a][b] = (f32x4){0.f, 0.f, 0.f, 0.f};

  for (int kt = 0; kt < 4; ++kt) {
    __syncthreads();
    {
      const uint4* gsrc = (const uint4*)(W1t + kt * 10240);
      uint4* ldst = (uint4*)Bls;
#pragma unroll
      for (int i = 0; i < 5; ++i) ldst[t + i * 256] = gsrc[t + i * 256];
    }
    __syncthreads();

    bfrag af[4];
#pragma unroll
    for (int fm = 0; fm < 4; ++fm) {
      int e = fm * 16 + ll;
      int bo = kt * 64 + lg * 16;
      af[fm] = *(const bfrag*)&Als[e * 128 + ((bo ^ ((e & 7) << 4)) >> 1)];
    }
    __builtin_amdgcn_s_setprio(1);
#pragma unroll
    for (int fn = 0; fn < 4; ++fn) {
      int j = wv * 64 + fn * 16 + ll;
      bfrag bf = *(const bfrag*)&Bls[j * 40 + lg * 8];
#pragma unroll
      for (int fm = 0; fm < 4; ++fm)
        acc[fm][fn] = __builtin_amdgcn_mfma_f32_16x16x32_bf16(af[fm], bf, acc[fm][fn], 0, 0, 0);
    }
    __builtin_amdgcn_s_setprio(0);
  }

  float bj[4], wj[4];
#pragma unroll
  for (int fn = 0; fn < 4; ++fn) {
    int j = wv * 64 + fn * 16 + ll;
    bj[fn] = b1[j];
    wj[fn] = W2[j];
  }
#pragma unroll
  for (int fm = 0; fm < 4; ++fm) {
    float pr[4] = {0.f, 0.f, 0.f, 0.f};
#pragma unroll
    for (int fn = 0; fn < 4; ++fn) {
#pragma unroll
      for (int r = 0; r < 4; ++r)
        pr[r] = fmaf(fmaxf(acc[fm][fn][r] + bj[fn], 0.f), wj[fn], pr[r]);
    }
#pragma unroll
    for (int m = 8; m >= 1; m >>= 1) {
#pragma unroll
      for (int r = 0; r < 4; ++r) pr[r] += __shfl_xor(pr[r], m);
    }
    if (ll == 0) {
#pragma unroll
      for (int r = 0; r < 4; ++r) red[wv][fm * 16 + lg * 4 + r] = pr[r];
    }
  }
  __syncthreads();
  if (t < 64) {
    int eg = e0 + t;
    if (eg < E) recon[eg] = red[0][t] + red[1][t] + red[2][t] + red[3][t] + b2[0];
  }
}

extern "C" void kernel_launch(void* const* d_in, const int* in_sizes, int n_in,
                              void* d_out, int out_size, void* d_ws, size_t ws_size,
                              hipStream_t stream) {
  const float* x = (const float*)d_in[0];
  const int* ei = (const int*)d_in[1];
  const float* gat_W = (const float*)d_in[2];
  const float* att_src = (const float*)d_in[3];
  const float* att_dst = (const float*)d_in[4];
  const float* gat_bias = (const float*)d_in[5];
  const float* bn1_g = (const float*)d_in[6];
  const float* bn1_b = (const float*)d_in[7];
  const float* gcn_W = (const float*)d_in[8];
  const float* gcn_bias = (const float*)d_in[9];
  const float* bn2_g = (const float*)d_in[10];
  const float* bn2_b = (const float*)d_in[11];
  const float* mu_W = (const float*)d_in[12];
  const float* mu_b = (const float*)d_in[13];
  const float* lv_W = (const float*)d_in[14];
  const float* lv_b = (const float*)d_in[15];
  const float* res_W = (const float*)d_in[16];
  const float* res_b = (const float*)d_in[17];
  const float* dec_W1 = (const float*)d_in[18];
  const float* dec_b1 = (const float*)d_in[19];
  const float* dec_W2 = (const float*)d_in[20];
  const float* dec_b2 = (const float*)d_in[21];
  const float* eps = (const float*)d_in[22];

  int N = in_sizes[0] / DIN;   // 50000
  int E = in_sizes[1] / 2;     // 800000
  int Et = E + N;
  int NB = (N + 255) / 256;    // scan chunks (<= 256)

  float* ws = (float*)d_ws;
  size_t off = 0;
  float* xp = ws; off += (size_t)N * 256;
  unsigned short* xpb = (unsigned short*)xp;    // bf16 xp rows, stride 512 ushorts
  unsigned short* xpb2 = (unsigned short*)xp;   // bf16 xp2 [N,64] (xpb dead by then)
  float* g2 = xp + (size_t)N * 64;
  float* rz = xp + (size_t)N * 192;
  unsigned short* rzb = (unsigned short*)rz;    // bf16 res_z [N,64]
  float* h1 = ws + off; off += (size_t)N * 128;
  float* a_src = ws + off; off += (size_t)2 * N;
  float* a_dst = ws + off; off += (size_t)2 * N;
  float* dinv = ws + off; off += N;
  float* P = ws + off; off += 128 * 128;
  float* PS = ws + off; off += 128 * 128;
  float* W2f = ws + off; off += 128 * 64;
  float* c2 = ws + off; off += 64;
  float* Wmuf = ws + off; off += 64 * 64;
  float* cmu = ws + off; off += 64;
  float* Wlvf = ws + off; off += 64 * 64;
  float* clv = ws + off; off += 64;
  unsigned short* W1t = (unsigned short*)(ws + off); off += 20480;   // 4*256*40 bf16
  unsigned short* Wtb = (unsigned short*)(ws + off); off += 32768;   // 256*256 bf16
  int* deg = (int*)(ws + off); off += N;
  int* offs = (int*)(ws + off); off += N;
  int* cursor = (int*)(ws + off); off += N;
  int* bsum = (int*)(ws + off); off += 256;
  int* csr = (int*)(ws + off); off += Et;

  float* recon = (float*)d_out;
  float* mu = recon + E;
  float* lv = mu + (size_t)N * LAT;

  // 0. weight preps + zero attn-score accumulators (a_src/a_dst contiguous)
  prep_W1<<<(4 * 256 * 40 + 255) / 256, 256, 0, stream>>>(dec_W1, W1t);
  prep_gatW<<<(256 * 256 + 255) / 256, 256, 0, stream>>>(gat_W, Wtb);
  hipMemsetAsync(a_src, 0, (size_t)4 * N * sizeof(float), stream);

  // 1. xp = x @ gat_W via MFMA; attention scores fused (atomic partials)
  dim3 gX(4, (N + 63) / 64);
  gemm_xp_mfma<<<gX, 256, 0, stream>>>(x, Wtb, att_src, att_dst, xpb, a_src, a_dst, N);

  // 2. CSR build (parallel 3-phase scan)
  hipMemsetAsync(deg, 0, (size_t)N * sizeof(int), stream);
  deg_count<<<(Et + 255) / 256, 256, 0, stream>>>(ei, E, Et, deg);
  bsum_kernel<<<NB, 256, 0, stream>>>(deg, N, bsum);
  bscan_kernel<<<1, 256, 0, stream>>>(bsum, NB);
  scan_apply<<<NB, 256, 0, stream>>>(deg, bsum, N, offs, cursor, dinv);
  csr_fill<<<(Et + 255) / 256, 256, 0, stream>>>(ei, E, Et, cursor, csr);

  // 3. fused GAT softmax + aggregation (8-way MLP unroll)
  gat_fused<<<(N + 3) / 4, 256, 0, stream>>>(offs, deg, csr, a_src, a_dst, xpb, gat_bias, h1, N);

  // 4. BN1 reduce+fold fused; xp2 (bf16) = h1 @ W2f + c2
  bn_stats<128><<<128, 256, 0, stream>>>(h1, N, P, PS);
  bn_fold_gcn<<<1, 256, 0, stream>>>(P, PS, 128, N, bn1_g, bn1_b, gcn_W, W2f, c2);
  dim3 gB((N + 63) / 64, 1);
  gemm64b<<<gB, 256, 0, stream>>>(h1, W2f, c2, xpb2, N, 64, 128);

  // 5. GCN aggregation (bf16 gather, 8-way MLP unroll)
  gcn_aggregate_bf<<<(N + 3) / 4, 256, 0, stream>>>(offs, deg, csr, xpb2, dinv, gcn_bias, g2, N);

  // 6. BN2 reduce+fold; fused tail (mu, lv, reparam, res GEMM in one kernel)
  bn_stats<64><<<128, 256, 0, stream>>>(g2, N, P, PS);
  bn_fold_mulv<<<1, 256, 0, stream>>>(P, PS, 128, N, bn2_g, bn2_b, mu_W, mu_b, lv_W, lv_b,
                                      Wmuf, cmu, Wlvf, clv);
  tail_fused<<<(N + 63) / 64, 256, 0, stream>>>(g2, Wmuf, cmu, Wlvf, clv, res_W, res_b, eps,
                                                mu, lv, rzb, N);

  // 7. MFMA decoder (40-pad B rows — measured best; setprio on MFMA cluster)
  decoder_mfma<<<(E + 63) / 64, 256, 0, stream>>>(ei, E, rzb, W1t, dec_b1, dec_W2, dec_b2, recon);
}

// Round 15
// 563.871 us; speedup vs baseline: 1.0198x; 1.0027x over previous
//
#include <hip/hip_runtime.h>
#include <math.h>

constexpr int DIN = 256;
constexpr int HID = 128;
constexpr int LAT = 64;

typedef short bfrag __attribute__((ext_vector_type(8)));   // 8 bf16 (4 VGPRs)
typedef float f32x4 __attribute__((ext_vector_type(4)));

__device__ __forceinline__ float4 ld4(const float* p) { return *reinterpret_cast<const float4*>(p); }
__device__ __forceinline__ void st4(float* p, float4 v) { *reinterpret_cast<float4*>(p) = v; }

__device__ __forceinline__ unsigned short f2bf(float f) {
  unsigned int u = __float_as_uint(f);
  unsigned int r = (u + 0x7FFFu + ((u >> 16) & 1u)) >> 16;  // RNE
  return (unsigned short)r;
}

__device__ __forceinline__ float bf2f(unsigned short u) {
  return __uint_as_float(((unsigned int)u) << 16);
}

// ---------------- f32 GEMM with bf16 output: Cb[M,N](bf16) = A[M,K] @ B[K,N] + crow ----------------
__global__ __launch_bounds__(256) void gemm64b(const float* __restrict__ A, const float* __restrict__ B,
                                               const float* __restrict__ crow, unsigned short* __restrict__ Cb,
                                               int M, int N, int K) {
  __shared__ float As[32][68];
  __shared__ float Bs[32][68];
  int t = threadIdx.x;
  int m0 = blockIdx.x * 64, n0 = blockIdx.y * 64;
  int tm = t & 15, tn = t >> 4;
  float acc[4][4];
#pragma unroll
  for (int i = 0; i < 4; i++)
#pragma unroll
    for (int j = 0; j < 4; j++) acc[i][j] = 0.f;

  for (int kt = 0; kt < K; kt += 32) {
#pragma unroll
    for (int i = 0; i < 2; ++i) {
      int f4 = t + i * 256;
      int m = f4 >> 3;
      int k4 = (f4 & 7) << 2;
      int gm = m0 + m;
      float4 v = make_float4(0.f, 0.f, 0.f, 0.f);
      if (gm < M) v = ld4(A + (size_t)gm * K + kt + k4);
      As[k4 + 0][m] = v.x; As[k4 + 1][m] = v.y; As[k4 + 2][m] = v.z; As[k4 + 3][m] = v.w;
    }
#pragma unroll
    for (int i = 0; i < 2; ++i) {
      int f4 = t + i * 256;
      int k = f4 >> 4;
      int n4 = (f4 & 15) << 2;
      float4 v = ld4(B + (size_t)(kt + k) * N + n0 + n4);
      st4(&Bs[k][n4], v);
    }
    __syncthreads();
#pragma unroll
    for (int k = 0; k < 32; ++k) {
      float4 a = ld4(&As[k][tm << 2]);
      float4 b = ld4(&Bs[k][tn << 2]);
      float av[4] = {a.x, a.y, a.z, a.w};
      float bv[4] = {b.x, b.y, b.z, b.w};
#pragma unroll
      for (int i = 0; i < 4; i++)
#pragma unroll
        for (int j = 0; j < 4; j++) acc[i][j] = fmaf(av[i], bv[j], acc[i][j]);
    }
    __syncthreads();
  }
#pragma unroll
  for (int i = 0; i < 4; ++i) {
    int gm = m0 + (tm << 2) + i;
    if (gm < M) {
      int nb = n0 + (tn << 2);
      ushort4 o;
      o.x = f2bf(acc[i][0] + crow[nb]);
      o.y = f2bf(acc[i][1] + crow[nb + 1]);
      o.z = f2bf(acc[i][2] + crow[nb + 2]);
      o.w = f2bf(acc[i][3] + crow[nb + 3]);
      *(ushort4*)(Cb + (size_t)gm * N + nb) = o;
    }
  }
}

// ---------------- MFMA GEMM: xpb = x(f32) @ Wtb^T, bf16 out; attn scores fused in epilogue ----------------
__global__ __launch_bounds__(256) void gemm_xp_mfma(const float* __restrict__ xf,
                                                    const unsigned short* __restrict__ Wtb,
                                                    const float* __restrict__ att_src,
                                                    const float* __restrict__ att_dst,
                                                    unsigned short* __restrict__ xpb,
                                                    float* __restrict__ a_src, float* __restrict__ a_dst, int M) {
  __shared__ unsigned short Als[64 * 256];
  __shared__ unsigned short Bls[64 * 256];
  int t = threadIdx.x;
  int wv = t >> 6, l = t & 63, lg = l >> 4, ll = l & 15;
  int cg = blockIdx.x;
  int rt = blockIdx.y;

  {
    int row = t >> 2, seg = t & 3;
    int gr = min(rt * 64 + row, M - 1);
    const float4* src = (const float4*)(xf + (size_t)gr * 256 + seg * 64);
    int swz = (row & 7) << 4;
#pragma unroll
    for (int c = 0; c < 8; ++c) {
      float4 a = src[2 * c], b = src[2 * c + 1];
      uint4 v;
      v.x = (unsigned)f2bf(a.x) | ((unsigned)f2bf(a.y) << 16);
      v.y = (unsigned)f2bf(a.z) | ((unsigned)f2bf(a.w) << 16);
      v.z = (unsigned)f2bf(b.x) | ((unsigned)f2bf(b.y) << 16);
      v.w = (unsigned)f2bf(b.z) | ((unsigned)f2bf(b.w) << 16);
      int bo = seg * 128 + c * 16;
      *(uint4*)((char*)Als + row * 512 + (bo ^ swz)) = v;
    }
  }
  {
    int col = t >> 2, seg = t & 3;
    const uint4* src = (const uint4*)(Wtb + (size_t)(cg * 64 + col) * 256 + seg * 64);
    int swz = (col & 7) << 4;
#pragma unroll
    for (int c = 0; c < 8; ++c) {
      int bo = seg * 128 + c * 16;
      *(uint4*)((char*)Bls + col * 512 + (bo ^ swz)) = src[c];
    }
  }
  __syncthreads();

  f32x4 acc[4];
#pragma unroll
  for (int i = 0; i < 4; ++i) acc[i] = (f32x4){0.f, 0.f, 0.f, 0.f};

#pragma unroll
  for (int kt = 0; kt < 8; ++kt) {
    int ar = wv * 16 + ll;
    bfrag af = *(const bfrag*)((char*)Als + ar * 512 + ((kt * 64 + lg * 16) ^ ((ar & 7) << 4)));
#pragma unroll
    for (int fn = 0; fn < 4; ++fn) {
      int bc = fn * 16 + ll;
      bfrag bf = *(const bfrag*)((char*)Bls + bc * 512 + ((kt * 64 + lg * 16) ^ ((bc & 7) << 4)));
      acc[fn] = __builtin_amdgcn_mfma_f32_16x16x32_bf16(af, bf, acc[fn], 0, 0, 0);
    }
  }

#pragma unroll
  for (int fn = 0; fn < 4; ++fn) {
#pragma unroll
    for (int r = 0; r < 4; ++r) {
      int row = rt * 64 + wv * 16 + lg * 4 + r;
      if (row < M) xpb[(size_t)row * 512 + cg * 64 + fn * 16 + ll] = f2bf(acc[fn][r]);
    }
  }

  // ---- fused attention-score partials ----
  int h = cg >> 1;
  int c0 = (cg & 1) * 64;
  float asv[4], adv[4];
#pragma unroll
  for (int fn = 0; fn < 4; ++fn) {
    asv[fn] = att_src[h * 128 + c0 + fn * 16 + ll];
    adv[fn] = att_dst[h * 128 + c0 + fn * 16 + ll];
  }
  float ps[4] = {0.f, 0.f, 0.f, 0.f}, pd[4] = {0.f, 0.f, 0.f, 0.f};
#pragma unroll
  for (int fn = 0; fn < 4; ++fn)
#pragma unroll
    for (int r = 0; r < 4; ++r) {
      ps[r] = fmaf(acc[fn][r], asv[fn], ps[r]);
      pd[r] = fmaf(acc[fn][r], adv[fn], pd[r]);
    }
#pragma unroll
  for (int m = 8; m >= 1; m >>= 1) {
#pragma unroll
    for (int r = 0; r < 4; ++r) { ps[r] += __shfl_xor(ps[r], m); pd[r] += __shfl_xor(pd[r], m); }
  }
  if (ll == 0) {
#pragma unroll
    for (int r = 0; r < 4; ++r) {
      int row = rt * 64 + wv * 16 + lg * 4 + r;
      if (row < M) {
        atomicAdd(&a_src[row * 2 + h], ps[r]);
        atomicAdd(&a_dst[row * 2 + h], pd[r]);
      }
    }
  }
}

// ---------------- CSR build ----------------
__global__ void deg_count(const int* __restrict__ ei, int E, int Et, int* __restrict__ deg) {
  int i = blockIdx.x * blockDim.x + threadIdx.x;
  if (i >= Et) return;
  int d = (i < E) ? ei[E + i] : (i - E);
  atomicAdd(&deg[d], 1);
}

__global__ __launch_bounds__(256) void bsum_kernel(const int* __restrict__ deg, int N, int* __restrict__ bsum) {
  int t = threadIdx.x;
  int i = blockIdx.x * 256 + t;
  int v = (i < N) ? deg[i] : 0;
#pragma unroll
  for (int m = 32; m >= 1; m >>= 1) v += __shfl_xor(v, m);
  __shared__ int sh[4];
  if ((t & 63) == 0) sh[t >> 6] = v;
  __syncthreads();
  if (t == 0) bsum[blockIdx.x] = sh[0] + sh[1] + sh[2] + sh[3];
}

__global__ __launch_bounds__(256) void bscan_kernel(int* __restrict__ bsum, int B) {
  __shared__ int sh[256];
  int t = threadIdx.x;
  int v = (t < B) ? bsum[t] : 0;
  sh[t] = v;
  __syncthreads();
  for (int d = 1; d < 256; d <<= 1) {
    int x = (t >= d) ? sh[t - d] : 0;
    __syncthreads();
    sh[t] += x;
    __syncthreads();
  }
  if (t < B) bsum[t] = sh[t] - v;
}

__global__ __launch_bounds__(256) void scan_apply(const int* __restrict__ deg, const int* __restrict__ bsum, int N,
                                                  int* __restrict__ offs, int* __restrict__ cursor,
                                                  float* __restrict__ dinv) {
  int t = threadIdx.x;
  int i = blockIdx.x * 256 + t;
  int v = (i < N) ? deg[i] : 0;
  __shared__ int sh[256];
  sh[t] = v;
  __syncthreads();
  for (int d = 1; d < 256; d <<= 1) {
    int x = (t >= d) ? sh[t - d] : 0;
    __syncthreads();
    sh[t] += x;
    __syncthreads();
  }
  if (i < N) {
    int off = bsum[blockIdx.x] + sh[t] - v;
    offs[i] = off;
    cursor[i] = off;
    dinv[i] = rsqrtf((float)v);   // deg >= 1 (self-loop)
  }
}

__global__ void csr_fill(const int* __restrict__ ei, int E, int Et, int* __restrict__ cursor, int* __restrict__ csr) {
  int i = blockIdx.x * blockDim.x + threadIdx.x;
  if (i >= Et) return;
  int s, d;
  if (i < E) { s = ei[i]; d = ei[E + i]; } else { s = i - E; d = i - E; }
  int pos = atomicAdd(&cursor[d], 1);
  csr[pos] = s;
}

// ---------------- FUSED GAT, no-max softmax, 8-way unrolled gather (wave per node) ----------------
__global__ __launch_bounds__(256) void gat_fused(const int* __restrict__ offs, const int* __restrict__ deg,
                                                 const int* __restrict__ csr, const float* __restrict__ a_src,
                                                 const float* __restrict__ a_dst,
                                                 const unsigned short* __restrict__ xpb,
                                                 const float* __restrict__ bias,
                                                 float* __restrict__ h1, int N) {
  int wid = threadIdx.x >> 6, lane = threadIdx.x & 63;
  int n = blockIdx.x * 4 + wid;
  if (n >= N) return;
  int off = offs[n], dg = deg[n];
  float ad0 = a_dst[n * 2], ad1 = a_dst[n * 2 + 1];
  const float2* as2 = (const float2*)a_src;

  float4 acc = make_float4(0.f, 0.f, 0.f, 0.f);
  float s0 = 0.f, s1 = 0.f;
  bool h0 = lane < 32;

#define GAT_STEP(aa, uu)                                         \
  {                                                              \
    float e0 = (aa).x + ad0; e0 = e0 >= 0.f ? e0 : 0.2f * e0;    \
    float e1 = (aa).y + ad1; e1 = e1 >= 0.f ? e1 : 0.2f * e1;    \
    float x0 = __expf(e0), x1 = __expf(e1);                      \
    s0 += x0; s1 += x1;                                          \
    float xa = h0 ? x0 : x1;                                     \
    acc.x = fmaf(bf2f((uu).x), xa, acc.x);                       \
    acc.y = fmaf(bf2f((uu).y), xa, acc.y);                       \
    acc.z = fmaf(bf2f((uu).z), xa, acc.z);                       \
    acc.w = fmaf(bf2f((uu).w), xa, acc.w);                       \
  }

  int k = 0;
  for (; k + 8 <= dg; k += 8) {
    int s_[8];
#pragma unroll
    for (int q = 0; q < 8; ++q) s_[q] = csr[off + k + q];
    float2 a_[8];
    ushort4 u_[8];
#pragma unroll
    for (int q = 0; q < 8; ++q) a_[q] = as2[s_[q]];
#pragma unroll
    for (int q = 0; q < 8; ++q) u_[q] = ((const ushort4*)(xpb + (size_t)s_[q] * 512))[lane];
#pragma unroll
    for (int q = 0; q < 8; ++q) GAT_STEP(a_[q], u_[q]);
  }
  for (; k + 4 <= dg; k += 4) {
    int sa = csr[off + k], sb = csr[off + k + 1], sc = csr[off + k + 2], sd = csr[off + k + 3];
    float2 aa = as2[sa], ab = as2[sb], ac = as2[sc], ad = as2[sd];
    ushort4 ua = ((const ushort4*)(xpb + (size_t)sa * 512))[lane];
    ushort4 ub = ((const ushort4*)(xpb + (size_t)sb * 512))[lane];
    ushort4 uc = ((const ushort4*)(xpb + (size_t)sc * 512))[lane];
    ushort4 ud = ((const ushort4*)(xpb + (size_t)sd * 512))[lane];
    GAT_STEP(aa, ua); GAT_STEP(ab, ub); GAT_STEP(ac, uc); GAT_STEP(ad, ud);
  }
  for (; k < dg; ++k) {
    int s = csr[off + k];
    float2 a = as2[s];
    ushort4 u = ((const ushort4*)(xpb + (size_t)s * 512))[lane];
    GAT_STEP(a, u);
  }
#undef GAT_STEP

  float r = h0 ? (1.f / s0) : (1.f / s1);
  acc.x *= r; acc.y *= r; acc.z *= r; acc.w *= r;

  float ox = __shfl_down(acc.x, 32);
  float oy = __shfl_down(acc.y, 32);
  float oz = __shfl_down(acc.z, 32);
  float ow = __shfl_down(acc.w, 32);
  if (h0) {
    int f4 = lane << 2;
    float4 b = ld4(bias + f4);
    float4 o;
    o.x = fmaxf(0.f, (acc.x + ox) * 0.5f + b.x);
    o.y = fmaxf(0.f, (acc.y + oy) * 0.5f + b.y);
    o.z = fmaxf(0.f, (acc.z + oz) * 0.5f + b.z);
    o.w = fmaxf(0.f, (acc.w + ow) * 0.5f + b.w);
    st4(h1 + (size_t)n * 128 + f4, o);
  }
}

// ---------------- BatchNorm stats ----------------
template <int C>
__global__ __launch_bounds__(256) void bn_stats(const float* __restrict__ h, int N, float* __restrict__ P,
                                                float* __restrict__ PS) {
  constexpr int R = 256 / C;
  __shared__ float sh[256], sh2[256];
  int t = threadIdx.x;
  int c = t % C, r = t / C;
  float s = 0.f, ss = 0.f;
  for (int n = blockIdx.x * R + r; n < N; n += gridDim.x * R) {
    float v = h[(size_t)n * C + c];
    s += v; ss += v * v;
  }
  sh[t] = s; sh2[t] = ss;
  __syncthreads();
  if (r == 0) {
#pragma unroll
    for (int i = 1; i < R; ++i) { s += sh[i * C + c]; ss += sh2[i * C + c]; }
    P[blockIdx.x * C + c] = s;
    PS[blockIdx.x * C + c] = ss;
  }
}

// ---------------- fused BN1 reduce + fold into GCN weights (1 block) ----------------
__global__ __launch_bounds__(256) void bn_fold_gcn(const float* __restrict__ P, const float* __restrict__ PS,
                                                   int G, int N, const float* __restrict__ g,
                                                   const float* __restrict__ b, const float* __restrict__ W,
                                                   float* __restrict__ Wf, float* __restrict__ cvec) {
  __shared__ float ssv[128], stv[128];
  int t = threadIdx.x;
  if (t < 128) {
    float s = 0.f, ss = 0.f;
    for (int i = 0; i < G; ++i) { s += P[i * 128 + t]; ss += PS[i * 128 + t]; }
    float mean = s / N;
    float var = ss / N - mean * mean;
    float sc = g[t] * rsqrtf(var + 1e-5f);
    ssv[t] = sc;
    stv[t] = b[t] - mean * sc;
  }
  __syncthreads();
  for (int i = t; i < 128 * 64; i += 256) {
    int k = i >> 6;
    Wf[i] = ssv[k] * W[i];
  }
  if (t < 64) {
    float c = 0.f;
    for (int k = 0; k < 128; ++k) c += stv[k] * W[k * 64 + t];
    cvec[t] = c;
  }
}

// ---------------- fused BN2 reduce + fold into mu/lv weights (1 block) ----------------
__global__ __launch_bounds__(256) void bn_fold_mulv(const float* __restrict__ P, const float* __restrict__ PS,
                                                    int G, int N, const float* __restrict__ g,
                                                    const float* __restrict__ b,
                                                    const float* __restrict__ Wmu, const float* __restrict__ mub,
                                                    const float* __restrict__ Wlv, const float* __restrict__ lvb,
                                                    float* __restrict__ Wmuf, float* __restrict__ cmu,
                                                    float* __restrict__ Wlvf, float* __restrict__ clv) {
  __shared__ float ssv[64], stv[64];
  int t = threadIdx.x;
  if (t < 64) {
    float s = 0.f, ss = 0.f;
    for (int i = 0; i < G; ++i) { s += P[i * 64 + t]; ss += PS[i * 64 + t]; }
    float mean = s / N;
    float var = ss / N - mean * mean;
    float sc = g[t] * rsqrtf(var + 1e-5f);
    ssv[t] = sc;
    stv[t] = b[t] - mean * sc;
  }
  __syncthreads();
  for (int i = t; i < 4096; i += 256) {
    int k = i >> 6;
    Wmuf[i] = ssv[k] * Wmu[i];
    Wlvf[i] = ssv[k] * Wlv[i];
  }
  if (t < 64) {
    float cm = mub[t], cl = lvb[t];
    for (int k = 0; k < 64; ++k) { cm += stv[k] * Wmu[k * 64 + t]; cl += stv[k] * Wlv[k * 64 + t]; }
    cmu[t] = cm; clv[t] = cl;
  }
}

// ---------------- GCN aggregation (bf16 gather, 8-way unrolled) ----------------
__global__ __launch_bounds__(256) void gcn_aggregate_bf(const int* __restrict__ offs, const int* __restrict__ deg,
                                                        const int* __restrict__ csr,
                                                        const unsigned short* __restrict__ xpb2,
                                                        const float* __restrict__ dinv, const float* __restrict__ bias,
                                                        float* __restrict__ g2, int N) {
  int wid = threadIdx.x >> 6, lane = threadIdx.x & 63;
  int n = blockIdx.x * 4 + wid;
  if (n >= N) return;
  int off = offs[n], dg = deg[n];
  float acc = 0.f;
  int k = 0;
  for (; k + 8 <= dg; k += 8) {
    int s_[8];
#pragma unroll
    for (int q = 0; q < 8; ++q) s_[q] = csr[off + k + q];
    float d_[8];
    unsigned short u_[8];
#pragma unroll
    for (int q = 0; q < 8; ++q) d_[q] = dinv[s_[q]];
#pragma unroll
    for (int q = 0; q < 8; ++q) u_[q] = xpb2[(size_t)s_[q] * 64 + lane];
#pragma unroll
    for (int q = 0; q < 8; ++q) acc = fmaf(bf2f(u_[q]), d_[q], acc);
  }
  for (; k + 4 <= dg; k += 4) {
    int sa = csr[off + k], sb = csr[off + k + 1], sc = csr[off + k + 2], sd = csr[off + k + 3];
    float da = dinv[sa], db = dinv[sb], dc = dinv[sc], dd = dinv[sd];
    unsigned short ua = xpb2[(size_t)sa * 64 + lane];
    unsigned short ub = xpb2[(size_t)sb * 64 + lane];
    unsigned short uc = xpb2[(size_t)sc * 64 + lane];
    unsigned short ud = xpb2[(size_t)sd * 64 + lane];
    acc = fmaf(bf2f(ua), da, acc);
    acc = fmaf(bf2f(ub), db, acc);
    acc = fmaf(bf2f(uc), dc, acc);
    acc = fmaf(bf2f(ud), dd, acc);
  }
  for (; k < dg; ++k) {
    int s = csr[off + k];
    acc = fmaf(bf2f(xpb2[(size_t)s * 64 + lane]), dinv[s], acc);
  }
  float v = acc * dinv[n] + bias[lane];
  g2[(size_t)n * 64 + lane] = fmaxf(v, 0.f);
}

// ---------------- fused tail: mu/lv GEMMs + reparam + res GEMM (64x64 tile, K=64) ----------------
__global__ __launch_bounds__(256) void tail_fused(const float* __restrict__ g2,
                                                  const float* __restrict__ Wmuf, const float* __restrict__ cmu,
                                                  const float* __restrict__ Wlvf, const float* __restrict__ clv,
                                                  const float* __restrict__ resW, const float* __restrict__ resb,
                                                  const float* __restrict__ eps,
                                                  float* __restrict__ mu, float* __restrict__ lv,
                                                  unsigned short* __restrict__ rzb, int N) {
  __shared__ float Gs[64][68];
  __shared__ float Wm[64][64];
  __shared__ float Wl[64][64];
  __shared__ float Rw[64][64];
  int t = threadIdx.x;
  int m0 = blockIdx.x * 64;
  int tm = t & 15, tn = t >> 4;

#pragma unroll
  for (int i = 0; i < 4; ++i) {
    int f4 = t + i * 256;
    int row = f4 >> 4;
    int k4 = (f4 & 15) << 2;
    int gr = m0 + row;
    float4 v = make_float4(0.f, 0.f, 0.f, 0.f);
    if (gr < N) v = ld4(g2 + (size_t)gr * 64 + k4);
    Gs[k4 + 0][row] = v.x; Gs[k4 + 1][row] = v.y; Gs[k4 + 2][row] = v.z; Gs[k4 + 3][row] = v.w;
    st4(&Wm[f4 >> 4][k4], ld4(Wmuf + f4 * 4));
    st4(&Wl[f4 >> 4][k4], ld4(Wlvf + f4 * 4));
    st4(&Rw[f4 >> 4][k4], ld4(resW + f4 * 4));
  }
  __syncthreads();

  float am[4][4], al[4][4];
#pragma unroll
  for (int i = 0; i < 4; ++i)
#pragma unroll
    for (int j = 0; j < 4; ++j) { am[i][j] = 0.f; al[i][j] = 0.f; }

#pragma unroll 8
  for (int k = 0; k < 64; ++k) {
    float4 a = ld4(&Gs[k][tm << 2]);
    float4 bm = ld4(&Wm[k][tn << 2]);
    float4 bl = ld4(&Wl[k][tn << 2]);
    float av[4] = {a.x, a.y, a.z, a.w};
    float bmv[4] = {bm.x, bm.y, bm.z, bm.w};
    float blv[4] = {bl.x, bl.y, bl.z, bl.w};
#pragma unroll
    for (int i = 0; i < 4; ++i)
#pragma unroll
      for (int j = 0; j < 4; ++j) {
        am[i][j] = fmaf(av[i], bmv[j], am[i][j]);
        al[i][j] = fmaf(av[i], blv[j], al[i][j]);
      }
  }

  int nb = tn << 2;
  float cm4[4] = {cmu[nb], cmu[nb + 1], cmu[nb + 2], cmu[nb + 3]};
  float cl4[4] = {clv[nb], clv[nb + 1], clv[nb + 2], clv[nb + 3]};
  float zreg[4][4];
#pragma unroll
  for (int i = 0; i < 4; ++i) {
    int gr = m0 + (tm << 2) + i;
    if (gr < N) {
      float4 ep = ld4(eps + (size_t)gr * 64 + nb);
      float epv[4] = {ep.x, ep.y, ep.z, ep.w};
      float muv[4], lvv[4];
#pragma unroll
      for (int j = 0; j < 4; ++j) {
        muv[j] = am[i][j] + cm4[j];
        lvv[j] = al[i][j] + cl4[j];
        zreg[i][j] = fmaf(epv[j], __expf(0.5f * lvv[j]), muv[j]);
      }
      st4(mu + (size_t)gr * 64 + nb, make_float4(muv[0], muv[1], muv[2], muv[3]));
      st4(lv + (size_t)gr * 64 + nb, make_float4(lvv[0], lvv[1], lvv[2], lvv[3]));
    } else {
#pragma unroll
      for (int j = 0; j < 4; ++j) zreg[i][j] = 0.f;
    }
  }

  __syncthreads();
#pragma unroll
  for (int i = 0; i < 4; ++i)
#pragma unroll
    for (int j = 0; j < 4; ++j) Gs[(tn << 2) + j][(tm << 2) + i] = zreg[i][j];
  __syncthreads();

  float ar[4][4];
#pragma unroll
  for (int i = 0; i < 4; ++i)
#pragma unroll
    for (int j = 0; j < 4; ++j) ar[i][j] = 0.f;
#pragma unroll 8
  for (int k = 0; k < 64; ++k) {
    float4 a = ld4(&Gs[k][tm << 2]);
    float4 b = ld4(&Rw[k][tn << 2]);
    float av[4] = {a.x, a.y, a.z, a.w};
    float bv[4] = {b.x, b.y, b.z, b.w};
#pragma unroll
    for (int i = 0; i < 4; ++i)
#pragma unroll
      for (int j = 0; j < 4; ++j) ar[i][j] = fmaf(av[i], bv[j], ar[i][j]);
  }
  float rb4[4] = {resb[nb], resb[nb + 1], resb[nb + 2], resb[nb + 3]};
#pragma unroll
  for (int i = 0; i < 4; ++i) {
    int gr = m0 + (tm << 2) + i;
    if (gr < N) {
      ushort4 o;
      o.x = f2bf(ar[i][0] + rb4[0]);
      o.y = f2bf(ar[i][1] + rb4[1]);
      o.z = f2bf(ar[i][2] + rb4[2]);
      o.w = f2bf(ar[i][3] + rb4[3]);
      *(ushort4*)(rzb + (size_t)gr * 64 + nb) = o;
    }
  }
}

// ---------------- prep gat_W -> transposed bf16 Wtb[col][k] ----------------
__global__ void prep_gatW(const float* __restrict__ W, unsigned short* __restrict__ Wtb) {
  int i = blockIdx.x * blockDim.x + threadIdx.x;
  if (i >= 256 * 256) return;
  int col = i >> 8, k = i & 255;
  Wtb[i] = f2bf(W[k * 256 + col]);
}

// ---------------- prep W1 → bf16 decoder layout [4 kt][256 j][40 kp] (padded) ----------------
__global__ void prep_W1(const float* __restrict__ W1, unsigned short* __restrict__ W1t) {
  int i = blockIdx.x * blockDim.x + threadIdx.x;
  if (i >= 4 * 256 * 40) return;
  int kt = i / 10240;
  int rem = i - kt * 10240;
  int j = rem / 40;
  int kp = rem - j * 40;
  float v = (kp < 32) ? W1[(size_t)(kt * 32 + kp) * 256 + j] : 0.f;
  W1t[i] = f2bf(v);
}

// ---------------- MFMA decoder (64 edges, 4 waves, B per-kt in LDS, 40-pad) ----------------
__global__ __launch_bounds__(256) void decoder_mfma(const int* __restrict__ ei, int E,
                                                    const unsigned short* __restrict__ rzb,
                                                    const unsigned short* __restrict__ W1t,
                                                    const float* __restrict__ b1, const float* __restrict__ W2,
                                                    const float* __restrict__ b2, float* __restrict__ recon) {
  __shared__ unsigned short Als[64 * 128];   // 16 KB
  __shared__ unsigned short Bls[256 * 40];   // 20 KB
  __shared__ float red[4][64];
  int t = threadIdx.x;
  int wv = t >> 6, l = t & 63;
  int lg = l >> 4, ll = l & 15;
  int e0 = blockIdx.x * 64;

  {
    int e = t >> 2;
    int part = (t >> 1) & 1;
    int half = t & 1;
    int eg = e0 + e;
    if (eg >= E) eg = E - 1;
    int r = (part == 0) ? ei[eg] : ei[E + eg];
    const uint4* gsrc = (const uint4*)(rzb + (size_t)r * 64 + half * 32);
    int bo0 = part * 128 + half * 64;
    int swz = (e & 7) << 4;
#pragma unroll
    for (int c = 0; c < 4; ++c) {
      uint4 v = gsrc[c];
      int bo = bo0 + c * 16;
      *(uint4*)&Als[e * 128 + ((bo ^ swz) >> 1)] = v;
    }
  }

  f32x4 acc[4][4];
#pragma unroll
  for (int a = 0; a < 4; ++a)
#pragma unroll
    for (int b = 0; b < 4; ++b) acc[a][b] = (f32x4){0.f, 0.f, 0.f, 0.f};

  for (int kt = 0; kt < 4; ++kt) {
    __syncthreads();
    {
      const uint4* gsrc = (const uint4*)(W1t + kt * 10240);
      uint4* ldst = (uint4*)Bls;
#pragma unroll
      for (int i = 0; i < 5; ++i) ldst[t + i * 256] = gsrc[t + i * 256];
    }
    __syncthreads();

    bfrag af[4];
#pragma unroll
    for (int fm = 0; fm < 4; ++fm) {
      int e = fm * 16 + ll;
      int bo = kt * 64 + lg * 16;
      af[fm] = *(const bfrag*)&Als[e * 128 + ((bo ^ ((e & 7) << 4)) >> 1)];
    }
#pragma unroll
    for (int fn = 0; fn < 4; ++fn) {
      int j = wv * 64 + fn * 16 + ll;
      bfrag bf = *(const bfrag*)&Bls[j * 40 + lg * 8];
#pragma unroll
      for (int fm = 0; fm < 4; ++fm)
        acc[fm][fn] = __builtin_amdgcn_mfma_f32_16x16x32_bf16(af[fm], bf, acc[fm][fn], 0, 0, 0);
    }
  }

  float bj[4], wj[4];
#pragma unroll
  for (int fn = 0; fn < 4; ++fn) {
    int j = wv * 64 + fn * 16 + ll;
    bj[fn] = b1[j];
    wj[fn] = W2[j];
  }
#pragma unroll
  for (int fm = 0; fm < 4; ++fm) {
    float pr[4] = {0.f, 0.f, 0.f, 0.f};
#pragma unroll
    for (int fn = 0; fn < 4; ++fn) {
#pragma unroll
      for (int r = 0; r < 4; ++r)
        pr[r] = fmaf(fmaxf(acc[fm][fn][r] + bj[fn], 0.f), wj[fn], pr[r]);
    }
#pragma unroll
    for (int m = 8; m >= 1; m >>= 1) {
#pragma unroll
      for (int r = 0; r < 4; ++r) pr[r] += __shfl_xor(pr[r], m);
    }
    if (ll == 0) {
#pragma unroll
      for (int r = 0; r < 4; ++r) red[wv][fm * 16 + lg * 4 + r] = pr[r];
    }
  }
  __syncthreads();
  if (t < 64) {
    int eg = e0 + t;
    if (eg < E) recon[eg] = red[0][t] + red[1][t] + red[2][t] + red[3][t] + b2[0];
  }
}

extern "C" void kernel_launch(void* const* d_in, const int* in_sizes, int n_in,
                              void* d_out, int out_size, void* d_ws, size_t ws_size,
                              hipStream_t stream) {
  const float* x = (const float*)d_in[0];
  const int* ei = (const int*)d_in[1];
  const float* gat_W = (const float*)d_in[2];
  const float* att_src = (const float*)d_in[3];
  const float* att_dst = (const float*)d_in[4];
  const float* gat_bias = (const float*)d_in[5];
  const float* bn1_g = (const float*)d_in[6];
  const float* bn1_b = (const float*)d_in[7];
  const float* gcn_W = (const float*)d_in[8];
  const float* gcn_bias = (const float*)d_in[9];
  const float* bn2_g = (const float*)d_in[10];
  const float* bn2_b = (const float*)d_in[11];
  const float* mu_W = (const float*)d_in[12];
  const float* mu_b = (const float*)d_in[13];
  const float* lv_W = (const float*)d_in[14];
  const float* lv_b = (const float*)d_in[15];
  const float* res_W = (const float*)d_in[16];
  const float* res_b = (const float*)d_in[17];
  const float* dec_W1 = (const float*)d_in[18];
  const float* dec_b1 = (const float*)d_in[19];
  const float* dec_W2 = (const float*)d_in[20];
  const float* dec_b2 = (const float*)d_in[21];
  const float* eps = (const float*)d_in[22];

  int N = in_sizes[0] / DIN;   // 50000
  int E = in_sizes[1] / 2;     // 800000
  int Et = E + N;
  int NB = (N + 255) / 256;    // scan chunks (<= 256)

  float* ws = (float*)d_ws;
  size_t off = 0;
  float* xp = ws; off += (size_t)N * 256;
  unsigned short* xpb = (unsigned short*)xp;    // bf16 xp rows, stride 512 ushorts
  unsigned short* xpb2 = (unsigned short*)xp;   // bf16 xp2 [N,64] (xpb dead by then)
  float* g2 = xp + (size_t)N * 64;
  float* rz = xp + (size_t)N * 192;
  unsigned short* rzb = (unsigned short*)rz;    // bf16 res_z [N,64]
  float* h1 = ws + off; off += (size_t)N * 128;
  float* a_src = ws + off; off += (size_t)2 * N;
  float* a_dst = ws + off; off += (size_t)2 * N;
  float* dinv = ws + off; off += N;
  float* P = ws + off; off += 128 * 128;
  float* PS = ws + off; off += 128 * 128;
  float* W2f = ws + off; off += 128 * 64;
  float* c2 = ws + off; off += 64;
  float* Wmuf = ws + off; off += 64 * 64;
  float* cmu = ws + off; off += 64;
  float* Wlvf = ws + off; off += 64 * 64;
  float* clv = ws + off; off += 64;
  unsigned short* W1t = (unsigned short*)(ws + off); off += 20480;   // 4*256*40 bf16
  unsigned short* Wtb = (unsigned short*)(ws + off); off += 32768;   // 256*256 bf16
  int* deg = (int*)(ws + off); off += N;
  int* offs = (int*)(ws + off); off += N;
  int* cursor = (int*)(ws + off); off += N;
  int* bsum = (int*)(ws + off); off += 256;
  int* csr = (int*)(ws + off); off += Et;

  float* recon = (float*)d_out;
  float* mu = recon + E;
  float* lv = mu + (size_t)N * LAT;

  // 0. weight preps + zero attn-score accumulators (a_src/a_dst contiguous)
  prep_W1<<<(4 * 256 * 40 + 255) / 256, 256, 0, stream>>>(dec_W1, W1t);
  prep_gatW<<<(256 * 256 + 255) / 256, 256, 0, stream>>>(gat_W, Wtb);
  hipMemsetAsync(a_src, 0, (size_t)4 * N * sizeof(float), stream);

  // 1. xp = x @ gat_W via MFMA; attention scores fused (atomic partials)
  dim3 gX(4, (N + 63) / 64);
  gemm_xp_mfma<<<gX, 256, 0, stream>>>(x, Wtb, att_src, att_dst, xpb, a_src, a_dst, N);

  // 2. CSR build (parallel 3-phase scan)
  hipMemsetAsync(deg, 0, (size_t)N * sizeof(int), stream);
  deg_count<<<(Et + 255) / 256, 256, 0, stream>>>(ei, E, Et, deg);
  bsum_kernel<<<NB, 256, 0, stream>>>(deg, N, bsum);
  bscan_kernel<<<1, 256, 0, stream>>>(bsum, NB);
  scan_apply<<<NB, 256, 0, stream>>>(deg, bsum, N, offs, cursor, dinv);
  csr_fill<<<(Et + 255) / 256, 256, 0, stream>>>(ei, E, Et, cursor, csr);

  // 3. fused GAT softmax + aggregation (8-way MLP unroll)
  gat_fused<<<(N + 3) / 4, 256, 0, stream>>>(offs, deg, csr, a_src, a_dst, xpb, gat_bias, h1, N);

  // 4. BN1 reduce+fold fused; xp2 (bf16) = h1 @ W2f + c2
  bn_stats<128><<<128, 256, 0, stream>>>(h1, N, P, PS);
  bn_fold_gcn<<<1, 256, 0, stream>>>(P, PS, 128, N, bn1_g, bn1_b, gcn_W, W2f, c2);
  dim3 gB((N + 63) / 64, 1);
  gemm64b<<<gB, 256, 0, stream>>>(h1, W2f, c2, xpb2, N, 64, 128);

  // 5. GCN aggregation (bf16 gather, 8-way MLP unroll)
  gcn_aggregate_bf<<<(N + 3) / 4, 256, 0, stream>>>(offs, deg, csr, xpb2, dinv, gcn_bias, g2, N);

  // 6. BN2 reduce+fold; fused tail (mu, lv, reparam, res GEMM in one kernel)
  bn_stats<64><<<128, 256, 0, stream>>>(g2, N, P, PS);
  bn_fold_mulv<<<1, 256, 0, stream>>>(P, PS, 128, N, bn2_g, bn2_b, mu_W, mu_b, lv_W, lv_b,
                                      Wmuf, cmu, Wlvf, clv);
  tail_fused<<<(N + 63) / 64, 256, 0, stream>>>(g2, Wmuf, cmu, Wlvf, clv, res_W, res_b, eps,
                                                mu, lv, rzb, N);

  // 7. MFMA decoder (40-pad B rows, no setprio — measured-best round-11 config)
  decoder_mfma<<<(E + 63) / 64, 256, 0, stream>>>(ei, E, rzb, W1t, dec_b1, dec_W2, dec_b2, recon);
}